// Round 7
// baseline (965.171 us; speedup 1.0000x reference)
//
#include <hip/hip_runtime.h>
#include <hip/hip_bf16.h>

// Problem constants
#define NN 32768      // nodes
#define BB 1024       // graphs
#define PP 32         // nodes per graph
#define EE 65536      // edges
#define HH 768
#define KSEM 1024
#define KCAT 1536
#define KP1 4608

typedef __attribute__((ext_vector_type(8))) short bf16x8;
typedef __attribute__((ext_vector_type(4))) float f32x4;

__device__ __forceinline__ unsigned short f2bf(float f){
  union { float f; unsigned u; } v; v.f = f;
  unsigned r = v.u + 0x7FFFu + ((v.u >> 16) & 1u);
  return (unsigned short)(r >> 16);
}
__device__ __forceinline__ float bf2f(unsigned short u){
  union { unsigned u; float f; } v; v.u = ((unsigned)u) << 16; return v.f;
}

__device__ __forceinline__ void gld_lds16(const void* g, void* l){
  __builtin_amdgcn_global_load_lds(
      (const __attribute__((address_space(1))) unsigned int*)g,
      (__attribute__((address_space(3))) unsigned int*)l, 16, 0, 0);
}

// ---------------- f32 -> bf16 cast, 8 elems/thread
__global__ __launch_bounds__(256) void k_cast(const float* __restrict__ in,
                                              unsigned short* __restrict__ out, int n8){
  int i = blockIdx.x * 256 + threadIdx.x;
  if (i >= n8) return;
  const float4* p = (const float4*)(in + (size_t)i * 8);
  float4 u0 = p[0], u1 = p[1];
  unsigned short vv[8];
  vv[0]=f2bf(u0.x); vv[1]=f2bf(u0.y); vv[2]=f2bf(u0.z); vv[3]=f2bf(u0.w);
  vv[4]=f2bf(u1.x); vv[5]=f2bf(u1.y); vv[6]=f2bf(u1.z); vv[7]=f2bf(u1.w);
  *(bf16x8*)(out + (size_t)i * 8) = *(bf16x8*)vv;
}

// ---------------- weight transpose: in (Kin x 768) f32 -> out[n*ostride + ooff + k] bf16
__global__ void k_transpose(const float* __restrict__ in, unsigned short* __restrict__ out,
                            int Kin, int ostride, int ooff){
  __shared__ float tile[32][33];
  int kb = blockIdx.x * 32, nb = blockIdx.y * 32;
  int tx = threadIdx.x & 31, ty = threadIdx.x >> 5; // 32 x 8
  #pragma unroll
  for (int i = ty; i < 32; i += 8)
    tile[i][tx] = in[(size_t)(kb + i) * 768 + nb + tx];
  __syncthreads();
  #pragma unroll
  for (int i = ty; i < 32; i += 8)
    out[(size_t)(nb + i) * ostride + ooff + kb + tx] = f2bf(tile[tx][i]);
}

// ================= 256x256 8-phase GEMM (T2+T3+T4+T5) — R4 schedule =================
// C(M x 768) = A(M x K) @ B; A bf16 row-major [M][K], Bt = [768][K] bf16.
// 512 threads = 8 waves (2M x 4N); per-wave output 128x64; BK=64; LDS 128KiB
// (A: 2 bufs x 256x64 bf16 = 64KB at offset 0; B: same at byte offset 65536).
// Swizzle: 32B-GRANULE (preserves gld_lds source coalescing — R6 lesson:
// 16B-granule 8-pos permutation cost ~36% in the memory pipe), 4 positions:
// byte_in_row ^= (row&3)<<5, pre-applied to the staging source column and
// applied on ds_read. 4-way residual bank conflict (1.58x, m136) vs R4's 8-way.
// EPI 0: h_text = relu(acc + spk+emo) -> h f32, hb16 = bf16 (htext)
// EPI 1: h = relu(acc) + h (in place f32); if WH, hb16 = bf16(h) for scatter2

#define BAR __builtin_amdgcn_s_barrier()
#define WAITL asm volatile("s_waitcnt lgkmcnt(0)" ::: "memory")
#define WAITV4 asm volatile("s_waitcnt vmcnt(4)" ::: "memory")
#define WAITV0 asm volatile("s_waitcnt vmcnt(0)" ::: "memory")

// stage one half-tile (128 rows x 64 cols bf16 = 16KB) = 2 gld_lds per thread
#define STG_A(buf,half,tile) { const unsigned short* s_ = aS + (size_t)((half)*128)*K + (tile)*64; \
    gld_lds16(s_,                 dA + (buf)*16384 + (half)*8192); \
    gld_lds16(s_ + (size_t)64*K,  dA + (buf)*16384 + (half)*8192 + 4096); }
#define STG_B(buf,half,tile) { const unsigned short* s_ = bS + (size_t)((half)*128)*K + (tile)*64; \
    gld_lds16(s_,                 dB + (buf)*16384 + (half)*8192); \
    gld_lds16(s_ + (size_t)64*K,  dB + (buf)*16384 + (half)*8192 + 4096); }
// load A frags for m-quadrant q (m = 2q, 2q+1), both k-slices
#define LDA(buf,q) { _Pragma("unroll") for (int jj=0;jj<2;++jj){ \
    const int R_ = wrow*128 + ((q)*2+jj)*16 + l15; const int sw_ = (R_&3)<<5; \
    af[jj][0] = *(const bf16x8*)((const char*)LDS + (buf)*32768 + R_*128 + ((kq)^sw_)); \
    af[jj][1] = *(const bf16x8*)((const char*)LDS + (buf)*32768 + R_*128 + ((64+kq)^sw_)); }}
// load all 4 B frags (n=0..3), both k-slices (once per K-tile, reused across 4 phases)
#define LDB(buf) { _Pragma("unroll") for (int nn=0;nn<4;++nn){ \
    const int R_ = wcol*64 + nn*16 + l15; const int sw_ = (R_&3)<<5; \
    bfr[nn][0] = *(const bf16x8*)((const char*)LDS + 65536 + (buf)*32768 + R_*128 + ((kq)^sw_)); \
    bfr[nn][1] = *(const bf16x8*)((const char*)LDS + 65536 + (buf)*32768 + R_*128 + ((64+kq)^sw_)); }}
#define MMA(q) { __builtin_amdgcn_s_setprio(1); \
    _Pragma("unroll") for (int jj=0;jj<2;++jj) _Pragma("unroll") for (int nn=0;nn<4;++nn){ \
      acc[(q)*2+jj][nn] = __builtin_amdgcn_mfma_f32_16x16x32_bf16(af[jj][0], bfr[nn][0], acc[(q)*2+jj][nn],0,0,0); \
      acc[(q)*2+jj][nn] = __builtin_amdgcn_mfma_f32_16x16x32_bf16(af[jj][1], bfr[nn][1], acc[(q)*2+jj][nn],0,0,0); } \
    __builtin_amdgcn_s_setprio(0); }

template<int EPI, int WH>
__global__ __launch_bounds__(512, 2) void k_gemm8(
    const unsigned short* __restrict__ A, const unsigned short* __restrict__ Bt, int K,
    float* __restrict__ h, unsigned short* __restrict__ hb16,
    const int* __restrict__ sid, const int* __restrict__ eid,
    const float* __restrict__ spk, const float* __restrict__ emo)
{
  __shared__ unsigned short LDS[65536];   // 128 KiB
  const int t = threadIdx.x;
  const int lane = t & 63, w = t >> 6;
  const int wrow = w >> 2, wcol = w & 3;

  // bijective XCD-chunked swizzle (gridDim.x % 8 == 0), col-fastest (3 col panels)
  const int bid = blockIdx.x;
  const int cpx = gridDim.x >> 3;
  const int wg = (bid & 7) * cpx + (bid >> 3);
  const int by = wg / 3, bx = wg - by * 3;
  const int brow = by * 256, bcol = bx * 256;

  f32x4 acc[8][4];
  #pragma unroll
  for (int m = 0; m < 8; ++m)
    #pragma unroll
    for (int n = 0; n < 4; ++n) acc[m][n] = f32x4{0.f,0.f,0.f,0.f};

  // staging: thread t covers row (t>>3) of a 64-row issue, cols 8*(t&7)..+8;
  // source column pre-swizzled by the row's 32B-granule key ((t>>3)&3)<<4
  // elements so the linear LDS dest ends up swizzled (rule 21). Both gld_lds
  // of one STG share the key since row and row+64 have the same (row&3).
  const int srow = t >> 3;
  const int scol = ((t & 7) * 8) ^ (((t >> 3) & 3) << 4);
  const unsigned short* aS = A  + (size_t)(brow + srow) * K + scol;
  const unsigned short* bS = Bt + (size_t)(bcol + srow) * K + scol;
  unsigned short* dA = LDS + (size_t)w * 512;        // + buf*16384 + half*8192 (+4096 for 2nd issue)
  unsigned short* dB = dA + 32768;
  const int l15 = lane & 15, kq = (lane >> 4) * 16;  // kq in bytes
  const int nkt = K >> 6, niter = nkt >> 1;

  bf16x8 af[2][2], bfr[4][2];

  // prologue: B(0), A(0), B(1); A(1) is issued in-loop at ph1/2 (steady-state shape)
  STG_B(0,0,0); STG_B(0,1,0);
  STG_A(0,0,0); STG_A(0,1,0);
  STG_B(1,0,1); STG_B(1,1,1);
  WAITV4;                       // tile 0 fully landed; B(1) (4 loads) may fly
  BAR;

  for (int i = 0; i < niter; ++i){
    const int t1 = 2*i+1;
    const int t2 = (2*i+2 < nkt) ? 2*i+2 : nkt-1;   // tail: re-fetch valid tile, data unused
    const int t3 = (2*i+3 < nkt) ? 2*i+3 : nkt-1;
    // ---- tile 2i from buf0 ----
    LDA(0,0); LDB(0); STG_A(1,0,t1);                 // buf1.A freed at prev ph8
    BAR; WAITL; MMA(0); BAR;                         // ph1
    LDA(0,1);         STG_A(1,1,t1);
    BAR; WAITL; MMA(1); BAR;                         // ph2
    LDA(0,2);         STG_B(0,0,t2);                 // buf0.B freed at ph1
    BAR; WAITL; MMA(2); BAR;                         // ph3
    LDA(0,3);         STG_B(0,1,t2);
    BAR; WAITL; MMA(3);
    WAITV4; BAR;                                     // ph4: A(t1) landed (leaves B(t2) x4)
    // ---- tile 2i+1 from buf1 ----
    LDA(1,0); LDB(1); STG_A(0,0,t2);                 // buf0.A freed at ph4
    BAR; WAITL; MMA(0); BAR;                         // ph5
    LDA(1,1);         STG_A(0,1,t2);
    BAR; WAITL; MMA(1); BAR;                         // ph6
    LDA(1,2);         STG_B(1,0,t3);                 // buf1.B freed at ph5
    BAR; WAITL; MMA(2); BAR;                         // ph7
    LDA(1,3);         STG_B(1,1,t3);
    BAR; WAITL; MMA(3);
    WAITV4; BAR;                                     // ph8: A(t2)+B(t2) landed (leaves B(t3) x4)
  }
  WAITV0;  // drain tail prefetches before exit

  // epilogue: C/D layout col=lane&15, row=(lane>>4)*4+reg
  #pragma unroll
  for (int m = 0; m < 8; ++m){
    #pragma unroll
    for (int n = 0; n < 4; ++n){
      const int col = bcol + wcol*64 + n*16 + l15;
      #pragma unroll
      for (int j = 0; j < 4; ++j){
        const int row = brow + wrow*128 + m*16 + ((lane>>4)*4) + j;
        float v = acc[m][n][j];
        if (EPI == 0){
          float e = spk[sid[row] * 768 + col] + emo[eid[row] * 768 + col];
          v = fmaxf(v + e, 0.f);
          h[(size_t)row * 768 + col] = v;
          hb16[(size_t)row * 768 + col] = f2bf(v);
        } else {
          v = fmaxf(v, 0.f) + h[(size_t)row * 768 + col];
          h[(size_t)row * 768 + col] = v;
          if (WH) hb16[(size_t)row * 768 + col] = f2bf(v);
        }
      }
    }
  }
}

// ================= 128x128 m97-style GEMM for the small (M=1024) shapes =================
// EPI 2: z = relu(acc + bias) -> obf at col base 3840, stride 4608 (edge_repr)
// EPI 3: hid = relu(acc + bias) -> of32 stride 768
template<int EPI>
__global__ __launch_bounds__(256) void k_gemm(
    const unsigned short* __restrict__ A, const unsigned short* __restrict__ Bt, int K,
    const float* __restrict__ bias,
    unsigned short* __restrict__ obf, float* __restrict__ of32)
{
  __shared__ unsigned short As[128*64];
  __shared__ unsigned short Bs[128*64];
  const int t = threadIdx.x;
  const int lane = t & 63, wave = t >> 6;

  const int bid = blockIdx.x;
  const int cpx = gridDim.x >> 3;
  const int wg = (bid & 7) * cpx + (bid >> 3);
  const int by = wg / 6;
  const int bx = wg - by * 6;
  const int brow = by * 128;
  const int bcol = bx * 128;

  const int wr = (wave >> 1) * 64, wc = (wave & 1) * 64;

  f32x4 acc[4][4];
  #pragma unroll
  for (int m = 0; m < 4; ++m)
    #pragma unroll
    for (int n = 0; n < 4; ++n)
      acc[m][n] = f32x4{0.f, 0.f, 0.f, 0.f};

  const int srow = wave * 8 + (lane >> 3);
  const int scol = (lane & 7) * 8;
  const int nkt = K >> 6;

  const unsigned short* a0 = A  + (size_t)(brow + srow) * K + scol;
  const unsigned short* b0 = Bt + (size_t)(bcol + srow) * K + scol;
  unsigned short* asdst = As + wave * 512;
  unsigned short* bsdst = Bs + wave * 512;

  for (int kt = 0; kt < nkt; ++kt){
    const unsigned short* ak = a0 + kt * 64;
    const unsigned short* bk = b0 + kt * 64;
    #pragma unroll
    for (int i = 0; i < 4; ++i)
      gld_lds16(ak + (size_t)i * 32 * K, asdst + i * 2048);
    #pragma unroll
    for (int i = 0; i < 4; ++i)
      gld_lds16(bk + (size_t)i * 32 * K, bsdst + i * 2048);
    __syncthreads();

    #pragma unroll
    for (int ks = 0; ks < 2; ++ks){
      bf16x8 af[4], bfr[4];
      const int kb = ks * 64 + ((lane >> 4) * 16);
      #pragma unroll
      for (int m = 0; m < 4; ++m)
        af[m] = *(const bf16x8*)((const char*)As + (wr + m * 16 + (lane & 15)) * 128 + kb);
      #pragma unroll
      for (int n = 0; n < 4; ++n)
        bfr[n] = *(const bf16x8*)((const char*)Bs + (wc + n * 16 + (lane & 15)) * 128 + kb);
      #pragma unroll
      for (int m = 0; m < 4; ++m)
        #pragma unroll
        for (int n = 0; n < 4; ++n)
          acc[m][n] = __builtin_amdgcn_mfma_f32_16x16x32_bf16(af[m], bfr[n], acc[m][n], 0, 0, 0);
    }
    __syncthreads();
  }

  #pragma unroll
  for (int m = 0; m < 4; ++m){
    #pragma unroll
    for (int n = 0; n < 4; ++n){
      int col = bcol + wc + n * 16 + (lane & 15);
      #pragma unroll
      for (int j = 0; j < 4; ++j){
        int row = brow + wr + m * 16 + ((lane >> 4) * 4) + j;
        float v = acc[m][n][j];
        if (EPI == 2){
          v = fmaxf(v + bias[col], 0.f);
          obf[(size_t)row * 4608 + 3840 + col] = f2bf(v);
        } else {
          v = fmaxf(v + bias[col], 0.f);
          of32[(size_t)row * 768 + col] = v;
        }
      }
    }
  }
}

// ---------------- per-graph segment sum from a bf16 source, LDS-staged
// reads hb (bf16 [NN][768]) once into LDS, writes acat[row] = [hb | msg]
__global__ __launch_bounds__(256) void k_scatter2(const unsigned short* __restrict__ hb,
                                                  const int* __restrict__ esrc,
                                                  const int* __restrict__ etgt,
                                                  unsigned short* __restrict__ acat){
  __shared__ unsigned short hsm[32 * 768];   // 48KB
  __shared__ int cnt[32];
  __shared__ unsigned char lst[32][64];
  const int g = blockIdx.x, t = threadIdx.x;
  const unsigned short* src = hb + (size_t)g * 32 * 768;
  #pragma unroll
  for (int i = 0; i < 12; ++i){
    const int o = (i * 256 + t) * 8;
    *(bf16x8*)(hsm + o) = *(const bf16x8*)(src + o);
  }
  if (t < 32) cnt[t] = 0;
  __syncthreads();
  if (t < 64){
    const int e = g * 64 + t;
    const int s = esrc[e] & 31, tg = etgt[e] & 31;   // intra-graph local ids
    const int slot = atomicAdd(&cnt[tg], 1);
    lst[tg][slot] = (unsigned char)s;
  }
  __syncthreads();
  const int c0 = t * 3;                              // 3 consecutive cols/thread
  for (int n = 0; n < 32; ++n){
    float s0 = 0.f, s1 = 0.f, s2 = 0.f;
    const int c = cnt[n];
    for (int e = 0; e < c; ++e){
      const unsigned short* r = hsm + (int)lst[n][e] * 768;
      s0 += bf2f(r[c0]); s1 += bf2f(r[c0+1]); s2 += bf2f(r[c0+2]);
    }
    unsigned short* oa = acat + (size_t)(g * 32 + n) * 1536;
    const unsigned short* hr = hsm + n * 768;
    oa[c0] = hr[c0]; oa[c0+1] = hr[c0+1]; oa[c0+2] = hr[c0+2];
    oa[768+c0] = f2bf(s0); oa[768+c0+1] = f2bf(s1); oa[768+c0+2] = f2bf(s2);
  }
}

// ---------------- per-graph: dist + gather h_c/h_t/h_dist into edge_repr
__global__ __launch_bounds__(256) void k_build(const float* __restrict__ h,
                                               const unsigned short* __restrict__ htext,
                                               const int* __restrict__ tni,
                                               const int* __restrict__ esrc,
                                               const int* __restrict__ etgt,
                                               const float* __restrict__ dist_emb,
                                               unsigned short* __restrict__ er){
  int g = blockIdx.x;
  int t = threadIdx.x;
  __shared__ int s_dist;
  int c = tni[g * 2 + 0], tt = tni[g * 2 + 1];
  if (t == 0){
    // reference quirk: first_edge indexed with LOCAL node ids -> graph 0's edges only
    int cu = c, tu = tt;
    for (int e = 0; e < 64; ++e){ if (esrc[e] == c){ cu = etgt[e]; break; } }
    for (int e = 0; e < 64; ++e){ if (esrc[e] == tt){ tu = etgt[e]; break; } }
    int d = cu - tu; if (d < 0) d = -d; if (d > 31) d = 31;
    s_dist = d;
  }
  __syncthreads();
  size_t rc = (size_t)(g * 32 + c) * 768, rt = (size_t)(g * 32 + tt) * 768;
  unsigned short* o = er + (size_t)g * 4608;
  int d = s_dist;
  for (int i = t; i < 768; i += 256){
    o[i]        = f2bf(h[rc + i]);
    o[768 + i]  = htext[rc + i];
    o[1536 + i] = f2bf(h[rt + i]);
    o[2304 + i] = htext[rt + i];
    o[3072 + i] = f2bf(dist_emb[(size_t)d * 768 + i]);
  }
}

// ---------------- logits: out[i] = hid[i,:] . W_p2 + b_p2
__global__ __launch_bounds__(256) void k_logits(const float* __restrict__ hid,
                                                const float* __restrict__ wp2,
                                                const float* __restrict__ bp2,
                                                float* __restrict__ out){
  int row = blockIdx.x * 4 + (threadIdx.x >> 6);
  int lane = threadIdx.x & 63;
  const float* r = hid + (size_t)row * 768;
  float s = 0.f;
  for (int j = lane; j < 768; j += 64) s += r[j] * wp2[j];
  #pragma unroll
  for (int off = 32; off; off >>= 1) s += __shfl_down(s, off);
  if (lane == 0) out[row] = s + bp2[0];
}

extern "C" void kernel_launch(void* const* d_in, const int* in_sizes, int n_in,
                              void* d_out, int out_size, void* d_ws, size_t ws_size,
                              hipStream_t stream){
  const float* x        = (const float*)d_in[0];
  const int*   sid      = (const int*)d_in[1];
  const int*   eid      = (const int*)d_in[2];
  const int*   esrc     = (const int*)d_in[3];
  const int*   etgt     = esrc + EE;
  const int*   tni      = (const int*)d_in[4];
  const float* expl     = (const float*)d_in[5];
  const float* W_sem    = (const float*)d_in[6];
  const float* spk      = (const float*)d_in[7];
  const float* emo      = (const float*)d_in[8];
  const float* w_self   = (const float*)d_in[9];
  const float* w_nbr    = (const float*)d_in[10];
  const float* dist_emb = (const float*)d_in[11];
  const float* W_expl   = (const float*)d_in[12];
  const float* b_expl   = (const float*)d_in[13];
  const float* W_p1     = (const float*)d_in[14];
  const float* b_p1     = (const float*)d_in[15];
  const float* W_p2     = (const float*)d_in[16];
  const float* b_p2     = (const float*)d_in[17];

  char* ws = (char*)d_ws;
  size_t off = 0;
  auto alloc = [&](size_t bytes) -> void* {
    void* p = ws + off; off += (bytes + 255) & ~(size_t)255; return p;
  };
  float*          h     = (float*)alloc((size_t)NN * HH * 4);
  unsigned short* htext = (unsigned short*)alloc((size_t)NN * HH * 2);
  unsigned short* hbf   = (unsigned short*)alloc((size_t)NN * HH * 2);
  unsigned short* acatA = (unsigned short*)alloc((size_t)NN * KCAT * 2);
  unsigned short* WsemT = (unsigned short*)alloc((size_t)HH * KSEM * 2);
  unsigned short* WcatT = (unsigned short*)alloc((size_t)3 * HH * KCAT * 2);
  unsigned short* WexplT= (unsigned short*)alloc((size_t)HH * HH * 2);
  unsigned short* Wp1T  = (unsigned short*)alloc((size_t)HH * KP1 * 2);
  unsigned short* erepr = (unsigned short*)alloc((size_t)BB * KP1 * 2);
  float*          hid   = (float*)alloc((size_t)BB * HH * 4);
  unsigned short* explbf= (unsigned short*)alloc((size_t)BB * HH * 2);
  // xbf aliases acatA: only live until sem GEMM completes; acatA first written after.
  unsigned short* xbf   = acatA;
  (void)ws_size; (void)in_sizes; (void)n_in; (void)out_size;

  // weight transposes (f32 -> bf16, [K][768] -> [768][K])
  k_transpose<<<dim3(KSEM/32, 24), 256, 0, stream>>>(W_sem, WsemT, KSEM, KSEM, 0);
  for (int l = 0; l < 3; ++l){
    k_transpose<<<dim3(24, 24), 256, 0, stream>>>(w_self + (size_t)l*HH*HH, WcatT + (size_t)l*HH*KCAT, HH, KCAT, 0);
    k_transpose<<<dim3(24, 24), 256, 0, stream>>>(w_nbr  + (size_t)l*HH*HH, WcatT + (size_t)l*HH*KCAT, HH, KCAT, HH);
  }
  k_transpose<<<dim3(24, 24), 256, 0, stream>>>(W_expl, WexplT, HH, HH, 0);
  k_transpose<<<dim3(KP1/32, 24), 256, 0, stream>>>(W_p1, Wp1T, KP1, KP1, 0);

  // activation casts f32 -> bf16
  k_cast<<<(NN*KSEM/8 + 255)/256, 256, 0, stream>>>(x, xbf, NN*KSEM/8);
  k_cast<<<(BB*HH/8 + 255)/256, 256, 0, stream>>>(expl, explbf, BB*HH/8);

  // h_text = relu(x @ W_sem + spk + emo)   [256^2 8-phase]
  k_gemm8<0,0><<<3*(NN/256), 512, 0, stream>>>(xbf, WsemT, KSEM,
      h, htext, sid, eid, spk, emo);

  // layer-0 A-buffer from htext (bf16 source)
  k_scatter2<<<BB, 256, 0, stream>>>(htext, esrc, etgt, acatA);

  // GNN layers [256^2 8-phase]; layers 0,1 also emit hbf for the next scatter
  k_gemm8<1,1><<<3*(NN/256), 512, 0, stream>>>(acatA, WcatT + (size_t)0*HH*KCAT, KCAT,
      h, hbf, nullptr, nullptr, nullptr, nullptr);
  k_scatter2<<<BB, 256, 0, stream>>>(hbf, esrc, etgt, acatA);
  k_gemm8<1,1><<<3*(NN/256), 512, 0, stream>>>(acatA, WcatT + (size_t)1*HH*KCAT, KCAT,
      h, hbf, nullptr, nullptr, nullptr, nullptr);
  k_scatter2<<<BB, 256, 0, stream>>>(hbf, esrc, etgt, acatA);
  k_gemm8<1,0><<<3*(NN/256), 512, 0, stream>>>(acatA, WcatT + (size_t)2*HH*KCAT, KCAT,
      h, nullptr, nullptr, nullptr, nullptr, nullptr);

  // z_teacher into edge_repr cols [3840,4608)  [128^2]
  k_gemm<2><<<6*(BB/128), 256, 0, stream>>>(explbf, WexplT, HH, b_expl, erepr, nullptr);

  // gather h_c/h_t/h_dist into edge_repr cols [0,3840)
  k_build<<<BB, 256, 0, stream>>>(h, htext, tni, esrc, etgt, dist_emb, erepr);

  // hid = relu(edge_repr @ W_p1 + b_p1)  [128^2]
  k_gemm<3><<<6*(BB/128), 256, 0, stream>>>(erepr, Wp1T, KP1, b_p1, nullptr, hid);

  // logits
  k_logits<<<BB/4, 256, 0, stream>>>(hid, W_p2, b_p2, (float*)d_out);
}

// Round 8
// 957.853 us; speedup vs baseline: 1.0076x; 1.0076x over previous
//
#include <hip/hip_runtime.h>
#include <hip/hip_bf16.h>

// Problem constants
#define NN 32768      // nodes
#define BB 1024       // graphs
#define PP 32         // nodes per graph
#define EE 65536      // edges
#define HH 768
#define KSEM 1024
#define KCAT 1536
#define KP1 4608

typedef __attribute__((ext_vector_type(8))) short bf16x8;
typedef __attribute__((ext_vector_type(4))) float f32x4;

__device__ __forceinline__ unsigned short f2bf(float f){
  union { float f; unsigned u; } v; v.f = f;
  unsigned r = v.u + 0x7FFFu + ((v.u >> 16) & 1u);
  return (unsigned short)(r >> 16);
}
__device__ __forceinline__ float bf2f(unsigned short u){
  union { unsigned u; float f; } v; v.u = ((unsigned)u) << 16; return v.f;
}

__device__ __forceinline__ void gld_lds16(const void* g, void* l){
  __builtin_amdgcn_global_load_lds(
      (const __attribute__((address_space(1))) unsigned int*)g,
      (__attribute__((address_space(3))) unsigned int*)l, 16, 0, 0);
}

// ---------------- f32 -> bf16 cast, 8 elems/thread
__global__ __launch_bounds__(256) void k_cast(const float* __restrict__ in,
                                              unsigned short* __restrict__ out, int n8){
  int i = blockIdx.x * 256 + threadIdx.x;
  if (i >= n8) return;
  const float4* p = (const float4*)(in + (size_t)i * 8);
  float4 u0 = p[0], u1 = p[1];
  unsigned short vv[8];
  vv[0]=f2bf(u0.x); vv[1]=f2bf(u0.y); vv[2]=f2bf(u0.z); vv[3]=f2bf(u0.w);
  vv[4]=f2bf(u1.x); vv[5]=f2bf(u1.y); vv[6]=f2bf(u1.z); vv[7]=f2bf(u1.w);
  *(bf16x8*)(out + (size_t)i * 8) = *(bf16x8*)vv;
}

// ---------------- weight transpose: in (Kin x 768) f32 -> out[n*ostride + ooff + k] bf16
__global__ void k_transpose(const float* __restrict__ in, unsigned short* __restrict__ out,
                            int Kin, int ostride, int ooff){
  __shared__ float tile[32][33];
  int kb = blockIdx.x * 32, nb = blockIdx.y * 32;
  int tx = threadIdx.x & 31, ty = threadIdx.x >> 5; // 32 x 8
  #pragma unroll
  for (int i = ty; i < 32; i += 8)
    tile[i][tx] = in[(size_t)(kb + i) * 768 + nb + tx];
  __syncthreads();
  #pragma unroll
  for (int i = ty; i < 32; i += 8)
    out[(size_t)(nb + i) * ostride + ooff + kb + tx] = f2bf(tile[tx][i]);
}

// ================= 256x256 8-phase GEMM (T2+T3+T4+T5) — R4 schedule, verbatim =================
// C(M x 768) = A(M x K) @ B; A bf16 row-major [M][K], Bt = [768][K] bf16.
// 512 threads = 8 waves (2M x 4N); per-wave output 128x64; BK=64; LDS 128KiB
// (A: 2 bufs x 256x64 bf16 = 64KB at offset 0; B: same at byte offset 65536).
// st_16x32 swizzle (m201 exact): read byte_in_row ^= ((row>>2)&1)<<5; source
// column pre-swizzled by the same involution (((t>>5)&1)<<4 elements).
// R6/R7 lesson: stronger keys (4-pos 32B, 8-pos 16B) fragment the gld_lds
// source into non-ascending runs -> staging-throughput-bound (-36%%). This
// 2-pos key is the coalescing-compatible optimum; residual 7M conflicts ~ 10us.
// EPI 0: h_text = relu(acc + spk+emo) -> h f32, hb16 = bf16 (htext)
// EPI 1: h = relu(acc) + h (in place f32); if WH, hb16 = bf16(h) for scatter2

#define BAR __builtin_amdgcn_s_barrier()
#define WAITL asm volatile("s_waitcnt lgkmcnt(0)" ::: "memory")
#define WAITV4 asm volatile("s_waitcnt vmcnt(4)" ::: "memory")
#define WAITV0 asm volatile("s_waitcnt vmcnt(0)" ::: "memory")

// stage one half-tile (128 rows x 64 cols bf16 = 16KB) = 2 gld_lds per thread
#define STG_A(buf,half,tile) { const unsigned short* s_ = aS + (size_t)((half)*128)*K + (tile)*64; \
    gld_lds16(s_,                 dA + (buf)*16384 + (half)*8192); \
    gld_lds16(s_ + (size_t)64*K,  dA + (buf)*16384 + (half)*8192 + 4096); }
#define STG_B(buf,half,tile) { const unsigned short* s_ = bS + (size_t)((half)*128)*K + (tile)*64; \
    gld_lds16(s_,                 dB + (buf)*16384 + (half)*8192); \
    gld_lds16(s_ + (size_t)64*K,  dB + (buf)*16384 + (half)*8192 + 4096); }
// load A frags for m-quadrant q (m = 2q, 2q+1), both k-slices
#define LDA(buf,q) { _Pragma("unroll") for (int jj=0;jj<2;++jj){ \
    const int R_ = wrow*128 + ((q)*2+jj)*16 + l15; const int sw_ = ((R_>>2)&1)<<5; \
    af[jj][0] = *(const bf16x8*)((const char*)LDS + (buf)*32768 + R_*128 + ((kq)^sw_)); \
    af[jj][1] = *(const bf16x8*)((const char*)LDS + (buf)*32768 + R_*128 + ((64+kq)^sw_)); }}
// load all 4 B frags (n=0..3), both k-slices (once per K-tile, reused across 4 phases)
#define LDB(buf) { _Pragma("unroll") for (int nn=0;nn<4;++nn){ \
    const int R_ = wcol*64 + nn*16 + l15; const int sw_ = ((R_>>2)&1)<<5; \
    bfr[nn][0] = *(const bf16x8*)((const char*)LDS + 65536 + (buf)*32768 + R_*128 + ((kq)^sw_)); \
    bfr[nn][1] = *(const bf16x8*)((const char*)LDS + 65536 + (buf)*32768 + R_*128 + ((64+kq)^sw_)); }}
#define MMA(q) { __builtin_amdgcn_s_setprio(1); \
    _Pragma("unroll") for (int jj=0;jj<2;++jj) _Pragma("unroll") for (int nn=0;nn<4;++nn){ \
      acc[(q)*2+jj][nn] = __builtin_amdgcn_mfma_f32_16x16x32_bf16(af[jj][0], bfr[nn][0], acc[(q)*2+jj][nn],0,0,0); \
      acc[(q)*2+jj][nn] = __builtin_amdgcn_mfma_f32_16x16x32_bf16(af[jj][1], bfr[nn][1], acc[(q)*2+jj][nn],0,0,0); } \
    __builtin_amdgcn_s_setprio(0); }

template<int EPI, int WH>
__global__ __launch_bounds__(512, 2) void k_gemm8(
    const unsigned short* __restrict__ A, const unsigned short* __restrict__ Bt, int K,
    float* __restrict__ h, unsigned short* __restrict__ hb16,
    const int* __restrict__ sid, const int* __restrict__ eid,
    const float* __restrict__ spk, const float* __restrict__ emo)
{
  __shared__ unsigned short LDS[65536];   // 128 KiB
  const int t = threadIdx.x;
  const int lane = t & 63, w = t >> 6;
  const int wrow = w >> 2, wcol = w & 3;

  // bijective XCD-chunked swizzle (gridDim.x % 8 == 0), col-fastest (3 col panels)
  const int bid = blockIdx.x;
  const int cpx = gridDim.x >> 3;
  const int wg = (bid & 7) * cpx + (bid >> 3);
  const int by = wg / 3, bx = wg - by * 3;
  const int brow = by * 256, bcol = bx * 256;

  f32x4 acc[8][4];
  #pragma unroll
  for (int m = 0; m < 8; ++m)
    #pragma unroll
    for (int n = 0; n < 4; ++n) acc[m][n] = f32x4{0.f,0.f,0.f,0.f};

  // staging: thread t covers row (t>>3) of a 64-row issue, cols 8*(t&7)..+8;
  // source column pre-swizzled (R4/m201 key) so linear LDS dest ends up swizzled.
  const int srow = t >> 3;
  const int scol = ((t & 7) * 8) ^ (((t >> 5) & 1) << 4);
  const unsigned short* aS = A  + (size_t)(brow + srow) * K + scol;
  const unsigned short* bS = Bt + (size_t)(bcol + srow) * K + scol;
  unsigned short* dA = LDS + (size_t)w * 512;        // + buf*16384 + half*8192 (+4096 for 2nd issue)
  unsigned short* dB = dA + 32768;
  const int l15 = lane & 15, kq = (lane >> 4) * 16;  // kq in bytes
  const int nkt = K >> 6, niter = nkt >> 1;

  bf16x8 af[2][2], bfr[4][2];

  // prologue: B(0), A(0), B(1); A(1) is issued in-loop at ph1/2 (steady-state shape)
  STG_B(0,0,0); STG_B(0,1,0);
  STG_A(0,0,0); STG_A(0,1,0);
  STG_B(1,0,1); STG_B(1,1,1);
  WAITV4;                       // tile 0 fully landed; B(1) (4 loads) may fly
  BAR;

  for (int i = 0; i < niter; ++i){
    const int t1 = 2*i+1;
    const int t2 = (2*i+2 < nkt) ? 2*i+2 : nkt-1;   // tail: re-fetch valid tile, data unused
    const int t3 = (2*i+3 < nkt) ? 2*i+3 : nkt-1;
    // ---- tile 2i from buf0 ----
    LDA(0,0); LDB(0); STG_A(1,0,t1);                 // buf1.A freed at prev ph8
    BAR; WAITL; MMA(0); BAR;                         // ph1
    LDA(0,1);         STG_A(1,1,t1);
    BAR; WAITL; MMA(1); BAR;                         // ph2
    LDA(0,2);         STG_B(0,0,t2);                 // buf0.B freed at ph1
    BAR; WAITL; MMA(2); BAR;                         // ph3
    LDA(0,3);         STG_B(0,1,t2);
    BAR; WAITL; MMA(3);
    WAITV4; BAR;                                     // ph4: A(t1) landed (leaves B(t2) x4)
    // ---- tile 2i+1 from buf1 ----
    LDA(1,0); LDB(1); STG_A(0,0,t2);                 // buf0.A freed at ph4
    BAR; WAITL; MMA(0); BAR;                         // ph5
    LDA(1,1);         STG_A(0,1,t2);
    BAR; WAITL; MMA(1); BAR;                         // ph6
    LDA(1,2);         STG_B(1,0,t3);                 // buf1.B freed at ph5
    BAR; WAITL; MMA(2); BAR;                         // ph7
    LDA(1,3);         STG_B(1,1,t3);
    BAR; WAITL; MMA(3);
    WAITV4; BAR;                                     // ph8: A(t2)+B(t2) landed (leaves B(t3) x4)
  }
  WAITV0;  // drain tail prefetches before exit

  // epilogue: C/D layout col=lane&15, row=(lane>>4)*4+reg
  #pragma unroll
  for (int m = 0; m < 8; ++m){
    #pragma unroll
    for (int n = 0; n < 4; ++n){
      const int col = bcol + wcol*64 + n*16 + l15;
      #pragma unroll
      for (int j = 0; j < 4; ++j){
        const int row = brow + wrow*128 + m*16 + ((lane>>4)*4) + j;
        float v = acc[m][n][j];
        if (EPI == 0){
          float e = spk[sid[row] * 768 + col] + emo[eid[row] * 768 + col];
          v = fmaxf(v + e, 0.f);
          h[(size_t)row * 768 + col] = v;
          hb16[(size_t)row * 768 + col] = f2bf(v);
        } else {
          v = fmaxf(v, 0.f) + h[(size_t)row * 768 + col];
          h[(size_t)row * 768 + col] = v;
          if (WH) hb16[(size_t)row * 768 + col] = f2bf(v);
        }
      }
    }
  }
}

// ================= 128x128 m97-style GEMM for the small (M=1024) shapes =================
// EPI 2: z = relu(acc + bias) -> obf at col base 3840, stride 4608 (edge_repr)
// EPI 3: hid = relu(acc + bias) -> of32 stride 768
template<int EPI>
__global__ __launch_bounds__(256) void k_gemm(
    const unsigned short* __restrict__ A, const unsigned short* __restrict__ Bt, int K,
    const float* __restrict__ bias,
    unsigned short* __restrict__ obf, float* __restrict__ of32)
{
  __shared__ unsigned short As[128*64];
  __shared__ unsigned short Bs[128*64];
  const int t = threadIdx.x;
  const int lane = t & 63, wave = t >> 6;

  const int bid = blockIdx.x;
  const int cpx = gridDim.x >> 3;
  const int wg = (bid & 7) * cpx + (bid >> 3);
  const int by = wg / 6;
  const int bx = wg - by * 6;
  const int brow = by * 128;
  const int bcol = bx * 128;

  const int wr = (wave >> 1) * 64, wc = (wave & 1) * 64;

  f32x4 acc[4][4];
  #pragma unroll
  for (int m = 0; m < 4; ++m)
    #pragma unroll
    for (int n = 0; n < 4; ++n)
      acc[m][n] = f32x4{0.f, 0.f, 0.f, 0.f};

  const int srow = wave * 8 + (lane >> 3);
  const int scol = (lane & 7) * 8;
  const int nkt = K >> 6;

  const unsigned short* a0 = A  + (size_t)(brow + srow) * K + scol;
  const unsigned short* b0 = Bt + (size_t)(bcol + srow) * K + scol;
  unsigned short* asdst = As + wave * 512;
  unsigned short* bsdst = Bs + wave * 512;

  for (int kt = 0; kt < nkt; ++kt){
    const unsigned short* ak = a0 + kt * 64;
    const unsigned short* bk = b0 + kt * 64;
    #pragma unroll
    for (int i = 0; i < 4; ++i)
      gld_lds16(ak + (size_t)i * 32 * K, asdst + i * 2048);
    #pragma unroll
    for (int i = 0; i < 4; ++i)
      gld_lds16(bk + (size_t)i * 32 * K, bsdst + i * 2048);
    __syncthreads();

    #pragma unroll
    for (int ks = 0; ks < 2; ++ks){
      bf16x8 af[4], bfr[4];
      const int kb = ks * 64 + ((lane >> 4) * 16);
      #pragma unroll
      for (int m = 0; m < 4; ++m)
        af[m] = *(const bf16x8*)((const char*)As + (wr + m * 16 + (lane & 15)) * 128 + kb);
      #pragma unroll
      for (int n = 0; n < 4; ++n)
        bfr[n] = *(const bf16x8*)((const char*)Bs + (wc + n * 16 + (lane & 15)) * 128 + kb);
      #pragma unroll
      for (int m = 0; m < 4; ++m)
        #pragma unroll
        for (int n = 0; n < 4; ++n)
          acc[m][n] = __builtin_amdgcn_mfma_f32_16x16x32_bf16(af[m], bfr[n], acc[m][n], 0, 0, 0);
    }
    __syncthreads();
  }

  #pragma unroll
  for (int m = 0; m < 4; ++m){
    #pragma unroll
    for (int n = 0; n < 4; ++n){
      int col = bcol + wc + n * 16 + (lane & 15);
      #pragma unroll
      for (int j = 0; j < 4; ++j){
        int row = brow + wr + m * 16 + ((lane >> 4) * 4) + j;
        float v = acc[m][n][j];
        if (EPI == 2){
          v = fmaxf(v + bias[col], 0.f);
          obf[(size_t)row * 4608 + 3840 + col] = f2bf(v);
        } else {
          v = fmaxf(v + bias[col], 0.f);
          of32[(size_t)row * 768 + col] = v;
        }
      }
    }
  }
}

// ---------------- per-graph segment sum from a bf16 source, LDS-staged
// reads hb (bf16 [NN][768]) once into LDS, writes acat[row] = [hb | msg]
__global__ __launch_bounds__(256) void k_scatter2(const unsigned short* __restrict__ hb,
                                                  const int* __restrict__ esrc,
                                                  const int* __restrict__ etgt,
                                                  unsigned short* __restrict__ acat){
  __shared__ unsigned short hsm[32 * 768];   // 48KB
  __shared__ int cnt[32];
  __shared__ unsigned char lst[32][64];
  const int g = blockIdx.x, t = threadIdx.x;
  const unsigned short* src = hb + (size_t)g * 32 * 768;
  #pragma unroll
  for (int i = 0; i < 12; ++i){
    const int o = (i * 256 + t) * 8;
    *(bf16x8*)(hsm + o) = *(const bf16x8*)(src + o);
  }
  if (t < 32) cnt[t] = 0;
  __syncthreads();
  if (t < 64){
    const int e = g * 64 + t;
    const int s = esrc[e] & 31, tg = etgt[e] & 31;   // intra-graph local ids
    const int slot = atomicAdd(&cnt[tg], 1);
    lst[tg][slot] = (unsigned char)s;
  }
  __syncthreads();
  const int c0 = t * 3;                              // 3 consecutive cols/thread
  for (int n = 0; n < 32; ++n){
    float s0 = 0.f, s1 = 0.f, s2 = 0.f;
    const int c = cnt[n];
    for (int e = 0; e < c; ++e){
      const unsigned short* r = hsm + (int)lst[n][e] * 768;
      s0 += bf2f(r[c0]); s1 += bf2f(r[c0+1]); s2 += bf2f(r[c0+2]);
    }
    unsigned short* oa = acat + (size_t)(g * 32 + n) * 1536;
    const unsigned short* hr = hsm + n * 768;
    oa[c0] = hr[c0]; oa[c0+1] = hr[c0+1]; oa[c0+2] = hr[c0+2];
    oa[768+c0] = f2bf(s0); oa[768+c0+1] = f2bf(s1); oa[768+c0+2] = f2bf(s2);
  }
}

// ---------------- per-graph: dist + gather h_c/h_t/h_dist into edge_repr
__global__ __launch_bounds__(256) void k_build(const float* __restrict__ h,
                                               const unsigned short* __restrict__ htext,
                                               const int* __restrict__ tni,
                                               const int* __restrict__ esrc,
                                               const int* __restrict__ etgt,
                                               const float* __restrict__ dist_emb,
                                               unsigned short* __restrict__ er){
  int g = blockIdx.x;
  int t = threadIdx.x;
  __shared__ int s_dist;
  int c = tni[g * 2 + 0], tt = tni[g * 2 + 1];
  if (t == 0){
    // reference quirk: first_edge indexed with LOCAL node ids -> graph 0's edges only
    int cu = c, tu = tt;
    for (int e = 0; e < 64; ++e){ if (esrc[e] == c){ cu = etgt[e]; break; } }
    for (int e = 0; e < 64; ++e){ if (esrc[e] == tt){ tu = etgt[e]; break; } }
    int d = cu - tu; if (d < 0) d = -d; if (d > 31) d = 31;
    s_dist = d;
  }
  __syncthreads();
  size_t rc = (size_t)(g * 32 + c) * 768, rt = (size_t)(g * 32 + tt) * 768;
  unsigned short* o = er + (size_t)g * 4608;
  int d = s_dist;
  for (int i = t; i < 768; i += 256){
    o[i]        = f2bf(h[rc + i]);
    o[768 + i]  = htext[rc + i];
    o[1536 + i] = f2bf(h[rt + i]);
    o[2304 + i] = htext[rt + i];
    o[3072 + i] = f2bf(dist_emb[(size_t)d * 768 + i]);
  }
}

// ---------------- logits: out[i] = hid[i,:] . W_p2 + b_p2
__global__ __launch_bounds__(256) void k_logits(const float* __restrict__ hid,
                                                const float* __restrict__ wp2,
                                                const float* __restrict__ bp2,
                                                float* __restrict__ out){
  int row = blockIdx.x * 4 + (threadIdx.x >> 6);
  int lane = threadIdx.x & 63;
  const float* r = hid + (size_t)row * 768;
  float s = 0.f;
  for (int j = lane; j < 768; j += 64) s += r[j] * wp2[j];
  #pragma unroll
  for (int off = 32; off; off >>= 1) s += __shfl_down(s, off);
  if (lane == 0) out[row] = s + bp2[0];
}

extern "C" void kernel_launch(void* const* d_in, const int* in_sizes, int n_in,
                              void* d_out, int out_size, void* d_ws, size_t ws_size,
                              hipStream_t stream){
  const float* x        = (const float*)d_in[0];
  const int*   sid      = (const int*)d_in[1];
  const int*   eid      = (const int*)d_in[2];
  const int*   esrc     = (const int*)d_in[3];
  const int*   etgt     = esrc + EE;
  const int*   tni      = (const int*)d_in[4];
  const float* expl     = (const float*)d_in[5];
  const float* W_sem    = (const float*)d_in[6];
  const float* spk      = (const float*)d_in[7];
  const float* emo      = (const float*)d_in[8];
  const float* w_self   = (const float*)d_in[9];
  const float* w_nbr    = (const float*)d_in[10];
  const float* dist_emb = (const float*)d_in[11];
  const float* W_expl   = (const float*)d_in[12];
  const float* b_expl   = (const float*)d_in[13];
  const float* W_p1     = (const float*)d_in[14];
  const float* b_p1     = (const float*)d_in[15];
  const float* W_p2     = (const float*)d_in[16];
  const float* b_p2     = (const float*)d_in[17];

  char* ws = (char*)d_ws;
  size_t off = 0;
  auto alloc = [&](size_t bytes) -> void* {
    void* p = ws + off; off += (bytes + 255) & ~(size_t)255; return p;
  };
  float*          h     = (float*)alloc((size_t)NN * HH * 4);
  unsigned short* htext = (unsigned short*)alloc((size_t)NN * HH * 2);
  unsigned short* hbf   = (unsigned short*)alloc((size_t)NN * HH * 2);
  unsigned short* acatA = (unsigned short*)alloc((size_t)NN * KCAT * 2);
  unsigned short* WsemT = (unsigned short*)alloc((size_t)HH * KSEM * 2);
  unsigned short* WcatT = (unsigned short*)alloc((size_t)3 * HH * KCAT * 2);
  unsigned short* WexplT= (unsigned short*)alloc((size_t)HH * HH * 2);
  unsigned short* Wp1T  = (unsigned short*)alloc((size_t)HH * KP1 * 2);
  unsigned short* erepr = (unsigned short*)alloc((size_t)BB * KP1 * 2);
  float*          hid   = (float*)alloc((size_t)BB * HH * 4);
  unsigned short* explbf= (unsigned short*)alloc((size_t)BB * HH * 2);
  // xbf aliases acatA: only live until sem GEMM completes; acatA first written after.
  unsigned short* xbf   = acatA;
  (void)ws_size; (void)in_sizes; (void)n_in; (void)out_size;

  // weight transposes (f32 -> bf16, [K][768] -> [768][K])
  k_transpose<<<dim3(KSEM/32, 24), 256, 0, stream>>>(W_sem, WsemT, KSEM, KSEM, 0);
  for (int l = 0; l < 3; ++l){
    k_transpose<<<dim3(24, 24), 256, 0, stream>>>(w_self + (size_t)l*HH*HH, WcatT + (size_t)l*HH*KCAT, HH, KCAT, 0);
    k_transpose<<<dim3(24, 24), 256, 0, stream>>>(w_nbr  + (size_t)l*HH*HH, WcatT + (size_t)l*HH*KCAT, HH, KCAT, HH);
  }
  k_transpose<<<dim3(24, 24), 256, 0, stream>>>(W_expl, WexplT, HH, HH, 0);
  k_transpose<<<dim3(KP1/32, 24), 256, 0, stream>>>(W_p1, Wp1T, KP1, KP1, 0);

  // activation casts f32 -> bf16
  k_cast<<<(NN*KSEM/8 + 255)/256, 256, 0, stream>>>(x, xbf, NN*KSEM/8);
  k_cast<<<(BB*HH/8 + 255)/256, 256, 0, stream>>>(expl, explbf, BB*HH/8);

  // h_text = relu(x @ W_sem + spk + emo)   [256^2 8-phase]
  k_gemm8<0,0><<<3*(NN/256), 512, 0, stream>>>(xbf, WsemT, KSEM,
      h, htext, sid, eid, spk, emo);

  // layer-0 A-buffer from htext (bf16 source)
  k_scatter2<<<BB, 256, 0, stream>>>(htext, esrc, etgt, acatA);

  // GNN layers [256^2 8-phase]; layers 0,1 also emit hbf for the next scatter
  k_gemm8<1,1><<<3*(NN/256), 512, 0, stream>>>(acatA, WcatT + (size_t)0*HH*KCAT, KCAT,
      h, hbf, nullptr, nullptr, nullptr, nullptr);
  k_scatter2<<<BB, 256, 0, stream>>>(hbf, esrc, etgt, acatA);
  k_gemm8<1,1><<<3*(NN/256), 512, 0, stream>>>(acatA, WcatT + (size_t)1*HH*KCAT, KCAT,
      h, hbf, nullptr, nullptr, nullptr, nullptr);
  k_scatter2<<<BB, 256, 0, stream>>>(hbf, esrc, etgt, acatA);
  k_gemm8<1,0><<<3*(NN/256), 512, 0, stream>>>(acatA, WcatT + (size_t)2*HH*KCAT, KCAT,
      h, nullptr, nullptr, nullptr, nullptr, nullptr);

  // z_teacher into edge_repr cols [3840,4608)  [128^2]
  k_gemm<2><<<6*(BB/128), 256, 0, stream>>>(explbf, WexplT, HH, b_expl, erepr, nullptr);

  // gather h_c/h_t/h_dist into edge_repr cols [0,3840)
  k_build<<<BB, 256, 0, stream>>>(h, htext, tni, esrc, etgt, dist_emb, erepr);

  // hid = relu(edge_repr @ W_p1 + b_p1)  [128^2]
  k_gemm<3><<<6*(BB/128), 256, 0, stream>>>(erepr, Wp1T, KP1, b_p1, nullptr, hid);

  // logits
  k_logits<<<BB/4, 256, 0, stream>>>(hid, W_p2, b_p2, (float*)d_out);
}

// Round 9
// 760.673 us; speedup vs baseline: 1.2688x; 1.2592x over previous
//
#include <hip/hip_runtime.h>
#include <hip/hip_bf16.h>

// Problem constants
#define NN 32768      // nodes
#define BB 1024       // graphs
#define PP 32         // nodes per graph
#define EE 65536      // edges
#define HH 768
#define KSEM 1024
#define KCAT 1536
#define KP1 4608

typedef __attribute__((ext_vector_type(8))) short bf16x8;
typedef __attribute__((ext_vector_type(4))) float f32x4;

__device__ __forceinline__ unsigned short f2bf(float f){
  union { float f; unsigned u; } v; v.f = f;
  unsigned r = v.u + 0x7FFFu + ((v.u >> 16) & 1u);
  return (unsigned short)(r >> 16);
}
__device__ __forceinline__ float bf2f(unsigned short u){
  union { unsigned u; float f; } v; v.u = ((unsigned)u) << 16; return v.f;
}

__device__ __forceinline__ void gld_lds16(const void* g, void* l){
  __builtin_amdgcn_global_load_lds(
      (const __attribute__((address_space(1))) unsigned int*)g,
      (__attribute__((address_space(3))) unsigned int*)l, 16, 0, 0);
}

// ---------------- f32 -> bf16 cast, 8 elems/thread
__global__ __launch_bounds__(256) void k_cast(const float* __restrict__ in,
                                              unsigned short* __restrict__ out, int n8){
  int i = blockIdx.x * 256 + threadIdx.x;
  if (i >= n8) return;
  const float4* p = (const float4*)(in + (size_t)i * 8);
  float4 u0 = p[0], u1 = p[1];
  unsigned short vv[8];
  vv[0]=f2bf(u0.x); vv[1]=f2bf(u0.y); vv[2]=f2bf(u0.z); vv[3]=f2bf(u0.w);
  vv[4]=f2bf(u1.x); vv[5]=f2bf(u1.y); vv[6]=f2bf(u1.z); vv[7]=f2bf(u1.w);
  *(bf16x8*)(out + (size_t)i * 8) = *(bf16x8*)vv;
}

// ---------------- weight transpose: in (Kin x 768) f32 -> out[n*ostride + ooff + k] bf16
__global__ void k_transpose(const float* __restrict__ in, unsigned short* __restrict__ out,
                            int Kin, int ostride, int ooff){
  __shared__ float tile[32][33];
  int kb = blockIdx.x * 32, nb = blockIdx.y * 32;
  int tx = threadIdx.x & 31, ty = threadIdx.x >> 5; // 32 x 8
  #pragma unroll
  for (int i = ty; i < 32; i += 8)
    tile[i][tx] = in[(size_t)(kb + i) * 768 + nb + tx];
  __syncthreads();
  #pragma unroll
  for (int i = ty; i < 32; i += 8)
    out[(size_t)(nb + i) * ostride + ooff + kb + tx] = f2bf(tile[tx][i]);
}

// ================= 256x256 8-phase GEMM (T2+T3+T4+T5) — R4 config, byte-identical =================
// C(M x 768) = A(M x K) @ B; A bf16 row-major [M][K], Bt = [768][K] bf16.
// 512 threads = 8 waves (2M x 4N); per-wave output 128x64; BK=64; LDS 128KiB
// (A: 2 bufs x 256x64 bf16 = 64KB at offset 0; B: same at byte offset 65536).
// st_16x32 swizzle: byte_in_row ^= ((row>>2)&1)<<5, applied on BOTH the staging
// global-source column (rule 21) and the ds_read address.
// EPI 0: h_text = relu(acc + spk[sid]+emo[eid]) -> h f32, htext bf16
// EPI 1: h = relu(acc) + h (in place f32)

#define BAR __builtin_amdgcn_s_barrier()
#define WAITL asm volatile("s_waitcnt lgkmcnt(0)" ::: "memory")
#define WAITV4 asm volatile("s_waitcnt vmcnt(4)" ::: "memory")
#define WAITV0 asm volatile("s_waitcnt vmcnt(0)" ::: "memory")

// stage one half-tile (128 rows x 64 cols bf16 = 16KB) = 2 gld_lds per thread
#define STG_A(buf,half,tile) { const unsigned short* s_ = aS + (size_t)((half)*128)*K + (tile)*64; \
    gld_lds16(s_,                 dA + (buf)*16384 + (half)*8192); \
    gld_lds16(s_ + (size_t)64*K,  dA + (buf)*16384 + (half)*8192 + 4096); }
#define STG_B(buf,half,tile) { const unsigned short* s_ = bS + (size_t)((half)*128)*K + (tile)*64; \
    gld_lds16(s_,                 dB + (buf)*16384 + (half)*8192); \
    gld_lds16(s_ + (size_t)64*K,  dB + (buf)*16384 + (half)*8192 + 4096); }
// load A frags for m-quadrant q (m = 2q, 2q+1), both k-slices
#define LDA(buf,q) { _Pragma("unroll") for (int jj=0;jj<2;++jj){ \
    const int R_ = wrow*128 + ((q)*2+jj)*16 + l15; const int sw_ = ((R_>>2)&1)<<5; \
    af[jj][0] = *(const bf16x8*)((const char*)LDS + (buf)*32768 + R_*128 + ((kq)^sw_)); \
    af[jj][1] = *(const bf16x8*)((const char*)LDS + (buf)*32768 + R_*128 + ((64+kq)^sw_)); }}
// load all 4 B frags (n=0..3), both k-slices (once per K-tile, reused across 4 phases)
#define LDB(buf) { _Pragma("unroll") for (int nn=0;nn<4;++nn){ \
    const int R_ = wcol*64 + nn*16 + l15; const int sw_ = ((R_>>2)&1)<<5; \
    bfr[nn][0] = *(const bf16x8*)((const char*)LDS + 65536 + (buf)*32768 + R_*128 + ((kq)^sw_)); \
    bfr[nn][1] = *(const bf16x8*)((const char*)LDS + 65536 + (buf)*32768 + R_*128 + ((64+kq)^sw_)); }}
#define MMA(q) { __builtin_amdgcn_s_setprio(1); \
    _Pragma("unroll") for (int jj=0;jj<2;++jj) _Pragma("unroll") for (int nn=0;nn<4;++nn){ \
      acc[(q)*2+jj][nn] = __builtin_amdgcn_mfma_f32_16x16x32_bf16(af[jj][0], bfr[nn][0], acc[(q)*2+jj][nn],0,0,0); \
      acc[(q)*2+jj][nn] = __builtin_amdgcn_mfma_f32_16x16x32_bf16(af[jj][1], bfr[nn][1], acc[(q)*2+jj][nn],0,0,0); } \
    __builtin_amdgcn_s_setprio(0); }

template<int EPI>
__global__ __launch_bounds__(512, 2) void k_gemm8(
    const unsigned short* __restrict__ A, const unsigned short* __restrict__ Bt, int K,
    float* __restrict__ h, unsigned short* __restrict__ htext,
    const int* __restrict__ sid, const int* __restrict__ eid,
    const float* __restrict__ spk, const float* __restrict__ emo)
{
  __shared__ unsigned short LDS[65536];   // 128 KiB
  const int t = threadIdx.x;
  const int lane = t & 63, w = t >> 6;
  const int wrow = w >> 2, wcol = w & 3;

  // bijective XCD-chunked swizzle (gridDim.x % 8 == 0), col-fastest (3 col panels)
  const int bid = blockIdx.x;
  const int cpx = gridDim.x >> 3;
  const int wg = (bid & 7) * cpx + (bid >> 3);
  const int by = wg / 3, bx = wg - by * 3;
  const int brow = by * 256, bcol = bx * 256;

  f32x4 acc[8][4];
  #pragma unroll
  for (int m = 0; m < 8; ++m)
    #pragma unroll
    for (int n = 0; n < 4; ++n) acc[m][n] = f32x4{0.f,0.f,0.f,0.f};

  // staging: thread t covers row (t>>3) of a 64-row issue, cols 8*(t&7)..+8,
  // with source column pre-swizzled so linear LDS ends up st_16x32-swizzled.
  const int srow = t >> 3;
  const int scol = ((t & 7) * 8) ^ (((t >> 5) & 1) << 4);
  const unsigned short* aS = A  + (size_t)(brow + srow) * K + scol;
  const unsigned short* bS = Bt + (size_t)(bcol + srow) * K + scol;
  unsigned short* dA = LDS + (size_t)w * 512;        // + buf*16384 + half*8192 (+4096 for 2nd issue)
  unsigned short* dB = dA + 32768;
  const int l15 = lane & 15, kq = (lane >> 4) * 16;  // kq in bytes
  const int nkt = K >> 6, niter = nkt >> 1;

  bf16x8 af[2][2], bfr[4][2];

  // prologue: B(0), A(0), B(1); A(1) is issued in-loop at ph1/2 (steady-state shape)
  STG_B(0,0,0); STG_B(0,1,0);
  STG_A(0,0,0); STG_A(0,1,0);
  STG_B(1,0,1); STG_B(1,1,1);
  WAITV4;                       // tile 0 fully landed; B(1) (4 loads) may fly
  BAR;

  for (int i = 0; i < niter; ++i){
    const int t1 = 2*i+1;
    const int t2 = (2*i+2 < nkt) ? 2*i+2 : nkt-1;   // tail: re-fetch valid tile, data unused
    const int t3 = (2*i+3 < nkt) ? 2*i+3 : nkt-1;
    // ---- tile 2i from buf0 ----
    LDA(0,0); LDB(0); STG_A(1,0,t1);                 // buf1.A freed at prev ph8
    BAR; WAITL; MMA(0); BAR;                         // ph1
    LDA(0,1);         STG_A(1,1,t1);
    BAR; WAITL; MMA(1); BAR;                         // ph2
    LDA(0,2);         STG_B(0,0,t2);                 // buf0.B freed at ph1
    BAR; WAITL; MMA(2); BAR;                         // ph3
    LDA(0,3);         STG_B(0,1,t2);
    BAR; WAITL; MMA(3);
    WAITV4; BAR;                                     // ph4: A(t1) landed (leaves B(t2) x4)
    // ---- tile 2i+1 from buf1 ----
    LDA(1,0); LDB(1); STG_A(0,0,t2);                 // buf0.A freed at ph4
    BAR; WAITL; MMA(0); BAR;                         // ph5
    LDA(1,1);         STG_A(0,1,t2);
    BAR; WAITL; MMA(1); BAR;                         // ph6
    LDA(1,2);         STG_B(1,0,t3);                 // buf1.B freed at ph5
    BAR; WAITL; MMA(2); BAR;                         // ph7
    LDA(1,3);         STG_B(1,1,t3);
    BAR; WAITL; MMA(3);
    WAITV4; BAR;                                     // ph8: A(t2)+B(t2) landed (leaves B(t3) x4)
  }
  WAITV0;  // drain tail prefetches before exit

  // epilogue: C/D layout col=lane&15, row=(lane>>4)*4+reg
  #pragma unroll
  for (int m = 0; m < 8; ++m){
    #pragma unroll
    for (int n = 0; n < 4; ++n){
      const int col = bcol + wcol*64 + n*16 + l15;
      #pragma unroll
      for (int j = 0; j < 4; ++j){
        const int row = brow + wrow*128 + m*16 + ((lane>>4)*4) + j;
        float v = acc[m][n][j];
        if (EPI == 0){
          float e = spk[sid[row] * 768 + col] + emo[eid[row] * 768 + col];
          v = fmaxf(v + e, 0.f);
          h[(size_t)row * 768 + col] = v;
          htext[(size_t)row * 768 + col] = f2bf(v);
        } else {
          v = fmaxf(v, 0.f) + h[(size_t)row * 768 + col];
          h[(size_t)row * 768 + col] = v;
        }
      }
    }
  }
}

// ================= 128x128 m97-style GEMM for the small (M=1024) shapes =================
// EPI 2: z = relu(acc + bias) -> obf at col base 3840, stride 4608 (edge_repr)
// EPI 3: hid = relu(acc + bias) -> of32 stride 768
template<int EPI>
__global__ __launch_bounds__(256) void k_gemm(
    const unsigned short* __restrict__ A, const unsigned short* __restrict__ Bt, int K,
    const float* __restrict__ bias,
    unsigned short* __restrict__ obf, float* __restrict__ of32)
{
  __shared__ unsigned short As[128*64];
  __shared__ unsigned short Bs[128*64];
  const int t = threadIdx.x;
  const int lane = t & 63, wave = t >> 6;

  const int bid = blockIdx.x;
  const int cpx = gridDim.x >> 3;
  const int wg = (bid & 7) * cpx + (bid >> 3);
  const int by = wg / 6;
  const int bx = wg - by * 6;
  const int brow = by * 128;
  const int bcol = bx * 128;

  const int wr = (wave >> 1) * 64, wc = (wave & 1) * 64;

  f32x4 acc[4][4];
  #pragma unroll
  for (int m = 0; m < 4; ++m)
    #pragma unroll
    for (int n = 0; n < 4; ++n)
      acc[m][n] = f32x4{0.f, 0.f, 0.f, 0.f};

  const int srow = wave * 8 + (lane >> 3);
  const int scol = (lane & 7) * 8;
  const int nkt = K >> 6;

  const unsigned short* a0 = A  + (size_t)(brow + srow) * K + scol;
  const unsigned short* b0 = Bt + (size_t)(bcol + srow) * K + scol;
  unsigned short* asdst = As + wave * 512;
  unsigned short* bsdst = Bs + wave * 512;

  for (int kt = 0; kt < nkt; ++kt){
    const unsigned short* ak = a0 + kt * 64;
    const unsigned short* bk = b0 + kt * 64;
    #pragma unroll
    for (int i = 0; i < 4; ++i)
      gld_lds16(ak + (size_t)i * 32 * K, asdst + i * 2048);
    #pragma unroll
    for (int i = 0; i < 4; ++i)
      gld_lds16(bk + (size_t)i * 32 * K, bsdst + i * 2048);
    __syncthreads();

    #pragma unroll
    for (int ks = 0; ks < 2; ++ks){
      bf16x8 af[4], bfr[4];
      const int kb = ks * 64 + ((lane >> 4) * 16);
      #pragma unroll
      for (int m = 0; m < 4; ++m)
        af[m] = *(const bf16x8*)((const char*)As + (wr + m * 16 + (lane & 15)) * 128 + kb);
      #pragma unroll
      for (int n = 0; n < 4; ++n)
        bfr[n] = *(const bf16x8*)((const char*)Bs + (wc + n * 16 + (lane & 15)) * 128 + kb);
      #pragma unroll
      for (int m = 0; m < 4; ++m)
        #pragma unroll
        for (int n = 0; n < 4; ++n)
          acc[m][n] = __builtin_amdgcn_mfma_f32_16x16x32_bf16(af[m], bfr[n], acc[m][n], 0, 0, 0);
    }
    __syncthreads();
  }

  #pragma unroll
  for (int m = 0; m < 4; ++m){
    #pragma unroll
    for (int n = 0; n < 4; ++n){
      int col = bcol + wc + n * 16 + (lane & 15);
      #pragma unroll
      for (int j = 0; j < 4; ++j){
        int row = brow + wr + m * 16 + ((lane >> 4) * 4) + j;
        float v = acc[m][n][j];
        if (EPI == 2){
          v = fmaxf(v + bias[col], 0.f);
          obf[(size_t)row * 4608 + 3840 + col] = f2bf(v);
        } else {
          v = fmaxf(v + bias[col], 0.f);
          of32[(size_t)row * 768 + col] = v;
        }
      }
    }
  }
}

// ---------------- per-graph segment sum + build bf16 [h | msg] A-buffer
// SAME signature/dataflow as R4 (reads f32 h, writes acat); body improved:
// stage the graph's 32 rows once in LDS as bf16 (coalesced float4 loads),
// sum from LDS, write acat coalesced. Single isolated delta vs R4.
__global__ __launch_bounds__(256) void k_scatter(const float* __restrict__ h,
                                                 const int* __restrict__ esrc,
                                                 const int* __restrict__ etgt,
                                                 unsigned short* __restrict__ acat){
  __shared__ unsigned short hsm[32 * 768];   // 48KB
  __shared__ int cnt[32];
  __shared__ unsigned char lst[32][64];
  const int g = blockIdx.x, t = threadIdx.x;
  const float* src = h + (size_t)g * 32 * 768;
  #pragma unroll
  for (int i = 0; i < 24; ++i){
    const int o = (i * 256 + t) * 4;
    float4 u = *(const float4*)(src + o);
    unsigned short vv[4] = { f2bf(u.x), f2bf(u.y), f2bf(u.z), f2bf(u.w) };
    *(unsigned long long*)(hsm + o) = *(const unsigned long long*)vv;
  }
  if (t < 32) cnt[t] = 0;
  __syncthreads();
  if (t < 64){
    const int e = g * 64 + t;
    const int s = esrc[e] & 31, tg = etgt[e] & 31;   // intra-graph local ids
    const int slot = atomicAdd(&cnt[tg], 1);
    lst[tg][slot] = (unsigned char)s;
  }
  __syncthreads();
  for (int n = 0; n < 32; ++n){
    float s0 = 0.f, s1 = 0.f, s2 = 0.f;
    const int c = cnt[n];
    for (int e = 0; e < c; ++e){
      const unsigned short* r = hsm + (int)lst[n][e] * 768;
      s0 += bf2f(r[t]); s1 += bf2f(r[t + 256]); s2 += bf2f(r[t + 512]);
    }
    unsigned short* oa = acat + (size_t)(g * 32 + n) * 1536;
    const unsigned short* hr = hsm + n * 768;
    oa[t]       = hr[t];
    oa[t + 256] = hr[t + 256];
    oa[t + 512] = hr[t + 512];
    oa[768 + t]       = f2bf(s0);
    oa[768 + t + 256] = f2bf(s1);
    oa[768 + t + 512] = f2bf(s2);
  }
}

// ---------------- per-graph: dist + gather h_c/h_t/h_dist into edge_repr
__global__ __launch_bounds__(256) void k_build(const float* __restrict__ h,
                                               const unsigned short* __restrict__ htext,
                                               const int* __restrict__ tni,
                                               const int* __restrict__ esrc,
                                               const int* __restrict__ etgt,
                                               const float* __restrict__ dist_emb,
                                               unsigned short* __restrict__ er){
  int g = blockIdx.x;
  int t = threadIdx.x;
  __shared__ int s_dist;
  int c = tni[g * 2 + 0], tt = tni[g * 2 + 1];
  if (t == 0){
    // reference quirk: first_edge indexed with LOCAL node ids -> graph 0's edges only
    int cu = c, tu = tt;
    for (int e = 0; e < 64; ++e){ if (esrc[e] == c){ cu = etgt[e]; break; } }
    for (int e = 0; e < 64; ++e){ if (esrc[e] == tt){ tu = etgt[e]; break; } }
    int d = cu - tu; if (d < 0) d = -d; if (d > 31) d = 31;
    s_dist = d;
  }
  __syncthreads();
  size_t rc = (size_t)(g * 32 + c) * 768, rt = (size_t)(g * 32 + tt) * 768;
  unsigned short* o = er + (size_t)g * 4608;
  int d = s_dist;
  for (int i = t; i < 768; i += 256){
    o[i]        = f2bf(h[rc + i]);
    o[768 + i]  = htext[rc + i];
    o[1536 + i] = f2bf(h[rt + i]);
    o[2304 + i] = htext[rt + i];
    o[3072 + i] = f2bf(dist_emb[(size_t)d * 768 + i]);
  }
}

// ---------------- logits: out[i] = hid[i,:] . W_p2 + b_p2
__global__ __launch_bounds__(256) void k_logits(const float* __restrict__ hid,
                                                const float* __restrict__ wp2,
                                                const float* __restrict__ bp2,
                                                float* __restrict__ out){
  int row = blockIdx.x * 4 + (threadIdx.x >> 6);
  int lane = threadIdx.x & 63;
  const float* r = hid + (size_t)row * 768;
  float s = 0.f;
  for (int j = lane; j < 768; j += 64) s += r[j] * wp2[j];
  #pragma unroll
  for (int off = 32; off; off >>= 1) s += __shfl_down(s, off);
  if (lane == 0) out[row] = s + bp2[0];
}

extern "C" void kernel_launch(void* const* d_in, const int* in_sizes, int n_in,
                              void* d_out, int out_size, void* d_ws, size_t ws_size,
                              hipStream_t stream){
  const float* x        = (const float*)d_in[0];
  const int*   sid      = (const int*)d_in[1];
  const int*   eid      = (const int*)d_in[2];
  const int*   esrc     = (const int*)d_in[3];
  const int*   etgt     = esrc + EE;
  const int*   tni      = (const int*)d_in[4];
  const float* expl     = (const float*)d_in[5];
  const float* W_sem    = (const float*)d_in[6];
  const float* spk      = (const float*)d_in[7];
  const float* emo      = (const float*)d_in[8];
  const float* w_self   = (const float*)d_in[9];
  const float* w_nbr    = (const float*)d_in[10];
  const float* dist_emb = (const float*)d_in[11];
  const float* W_expl   = (const float*)d_in[12];
  const float* b_expl   = (const float*)d_in[13];
  const float* W_p1     = (const float*)d_in[14];
  const float* b_p1     = (const float*)d_in[15];
  const float* W_p2     = (const float*)d_in[16];
  const float* b_p2     = (const float*)d_in[17];

  char* ws = (char*)d_ws;
  size_t off = 0;
  auto alloc = [&](size_t bytes) -> void* {
    void* p = ws + off; off += (bytes + 255) & ~(size_t)255; return p;
  };
  float*          h     = (float*)alloc((size_t)NN * HH * 4);
  unsigned short* htext = (unsigned short*)alloc((size_t)NN * HH * 2);
  unsigned short* acat  = (unsigned short*)alloc((size_t)NN * KCAT * 2);
  unsigned short* WsemT = (unsigned short*)alloc((size_t)HH * KSEM * 2);
  unsigned short* WcatT = (unsigned short*)alloc((size_t)3 * HH * KCAT * 2);
  unsigned short* WexplT= (unsigned short*)alloc((size_t)HH * HH * 2);
  unsigned short* Wp1T  = (unsigned short*)alloc((size_t)HH * KP1 * 2);
  unsigned short* erepr = (unsigned short*)alloc((size_t)BB * KP1 * 2);
  float*          hid   = (float*)alloc((size_t)BB * HH * 4);
  unsigned short* explbf= (unsigned short*)alloc((size_t)BB * HH * 2);
  // xbf aliases acat: only live until sem GEMM completes; acat first written after.
  unsigned short* xbf   = acat;
  (void)ws_size; (void)in_sizes; (void)n_in; (void)out_size;

  // weight transposes (f32 -> bf16, [K][768] -> [768][K])
  k_transpose<<<dim3(KSEM/32, 24), 256, 0, stream>>>(W_sem, WsemT, KSEM, KSEM, 0);
  for (int l = 0; l < 3; ++l){
    k_transpose<<<dim3(24, 24), 256, 0, stream>>>(w_self + (size_t)l*HH*HH, WcatT + (size_t)l*HH*KCAT, HH, KCAT, 0);
    k_transpose<<<dim3(24, 24), 256, 0, stream>>>(w_nbr  + (size_t)l*HH*HH, WcatT + (size_t)l*HH*KCAT, HH, KCAT, HH);
  }
  k_transpose<<<dim3(24, 24), 256, 0, stream>>>(W_expl, WexplT, HH, HH, 0);
  k_transpose<<<dim3(KP1/32, 24), 256, 0, stream>>>(W_p1, Wp1T, KP1, KP1, 0);

  // activation casts f32 -> bf16
  k_cast<<<(NN*KSEM/8 + 255)/256, 256, 0, stream>>>(x, xbf, NN*KSEM/8);
  k_cast<<<(BB*HH/8 + 255)/256, 256, 0, stream>>>(expl, explbf, BB*HH/8);

  // h_text = relu(x @ W_sem + spk + emo)  [256^2 8-phase]
  k_gemm8<0><<<3*(NN/256), 512, 0, stream>>>(xbf, WsemT, KSEM,
      h, htext, sid, eid, spk, emo);

  // 3 GNN layers  [256^2 8-phase]
  for (int l = 0; l < 3; ++l){
    k_scatter<<<BB, 256, 0, stream>>>(h, esrc, etgt, acat);
    k_gemm8<1><<<3*(NN/256), 512, 0, stream>>>(acat, WcatT + (size_t)l*HH*KCAT, KCAT,
        h, nullptr, nullptr, nullptr, nullptr, nullptr);
  }

  // z_teacher into edge_repr cols [3840,4608)  [128^2]
  k_gemm<2><<<6*(BB/128), 256, 0, stream>>>(explbf, WexplT, HH, b_expl, erepr, nullptr);

  // gather h_c/h_t/h_dist into edge_repr cols [0,3840)
  k_build<<<BB, 256, 0, stream>>>(h, htext, tni, esrc, etgt, dist_emb, erepr);

  // hid = relu(edge_repr @ W_p1 + b_p1)  [128^2]
  k_gemm<3><<<6*(BB/128), 256, 0, stream>>>(erepr, Wp1T, KP1, b_p1, nullptr, hid);

  // logits
  k_logits<<<BB/4, 256, 0, stream>>>(hid, W_p2, b_p2, (float*)d_out);
}

// Round 10
// 699.641 us; speedup vs baseline: 1.3795x; 1.0872x over previous
//
#include <hip/hip_runtime.h>
#include <hip/hip_bf16.h>

// Problem constants
#define NN 32768      // nodes
#define BB 1024       // graphs
#define PP 32         // nodes per graph
#define EE 65536      // edges
#define HH 768
#define KSEM 1024
#define KCAT 1536
#define KP1 4608

typedef __attribute__((ext_vector_type(8))) short bf16x8;
typedef __attribute__((ext_vector_type(4))) float f32x4;

__device__ __forceinline__ unsigned short f2bf(float f){
  union { float f; unsigned u; } v; v.f = f;
  unsigned r = v.u + 0x7FFFu + ((v.u >> 16) & 1u);
  return (unsigned short)(r >> 16);
}
__device__ __forceinline__ float bf2f(unsigned short u){
  union { unsigned u; float f; } v; v.u = ((unsigned)u) << 16; return v.f;
}

__device__ __forceinline__ void gld_lds16(const void* g, void* l){
  __builtin_amdgcn_global_load_lds(
      (const __attribute__((address_space(1))) unsigned int*)g,
      (__attribute__((address_space(3))) unsigned int*)l, 16, 0, 0);
}

// ---------------- f32 -> bf16 cast, 8 elems/thread
__global__ __launch_bounds__(256) void k_cast(const float* __restrict__ in,
                                              unsigned short* __restrict__ out, int n8){
  int i = blockIdx.x * 256 + threadIdx.x;
  if (i >= n8) return;
  const float4* p = (const float4*)(in + (size_t)i * 8);
  float4 u0 = p[0], u1 = p[1];
  unsigned short vv[8];
  vv[0]=f2bf(u0.x); vv[1]=f2bf(u0.y); vv[2]=f2bf(u0.z); vv[3]=f2bf(u0.w);
  vv[4]=f2bf(u1.x); vv[5]=f2bf(u1.y); vv[6]=f2bf(u1.z); vv[7]=f2bf(u1.w);
  *(bf16x8*)(out + (size_t)i * 8) = *(bf16x8*)vv;
}

// ---------------- weight transpose: in (Kin x 768) f32 -> out[n*ostride + ooff + k] bf16
__global__ void k_transpose(const float* __restrict__ in, unsigned short* __restrict__ out,
                            int Kin, int ostride, int ooff){
  __shared__ float tile[32][33];
  int kb = blockIdx.x * 32, nb = blockIdx.y * 32;
  int tx = threadIdx.x & 31, ty = threadIdx.x >> 5; // 32 x 8
  #pragma unroll
  for (int i = ty; i < 32; i += 8)
    tile[i][tx] = in[(size_t)(kb + i) * 768 + nb + tx];
  __syncthreads();
  #pragma unroll
  for (int i = ty; i < 32; i += 8)
    out[(size_t)(nb + i) * ostride + ooff + kb + tx] = f2bf(tile[tx][i]);
}

// ================= 256x256 8-phase GEMM (T2+T3+T4+T5) — R4/R9 schedule, FROZEN =================
// C(M x 768) = A(M x K) @ B; A bf16 row-major [M][K], Bt = [768][K] bf16.
// 512 threads = 8 waves (2M x 4N); per-wave output 128x64; BK=64; LDS 128KiB.
// st_16x32 swizzle: byte_in_row ^= ((row>>2)&1)<<5 on read; source pre-swizzled.
// ONLY epilogue changed vs R9: h is now stored as bf16 (hb). Residual chain,
// scatter and build all consume bf16 -> ~480MB less HBM traffic pipeline-wide.
// EPI 0: h_text = relu(acc + spk[sid]+emo[eid]) -> hb bf16, htext bf16
// EPI 1: h = relu(acc) + h (bf16 in place)

#define BAR __builtin_amdgcn_s_barrier()
#define WAITL asm volatile("s_waitcnt lgkmcnt(0)" ::: "memory")
#define WAITV4 asm volatile("s_waitcnt vmcnt(4)" ::: "memory")
#define WAITV0 asm volatile("s_waitcnt vmcnt(0)" ::: "memory")

// stage one half-tile (128 rows x 64 cols bf16 = 16KB) = 2 gld_lds per thread
#define STG_A(buf,half,tile) { const unsigned short* s_ = aS + (size_t)((half)*128)*K + (tile)*64; \
    gld_lds16(s_,                 dA + (buf)*16384 + (half)*8192); \
    gld_lds16(s_ + (size_t)64*K,  dA + (buf)*16384 + (half)*8192 + 4096); }
#define STG_B(buf,half,tile) { const unsigned short* s_ = bS + (size_t)((half)*128)*K + (tile)*64; \
    gld_lds16(s_,                 dB + (buf)*16384 + (half)*8192); \
    gld_lds16(s_ + (size_t)64*K,  dB + (buf)*16384 + (half)*8192 + 4096); }
// load A frags for m-quadrant q (m = 2q, 2q+1), both k-slices
#define LDA(buf,q) { _Pragma("unroll") for (int jj=0;jj<2;++jj){ \
    const int R_ = wrow*128 + ((q)*2+jj)*16 + l15; const int sw_ = ((R_>>2)&1)<<5; \
    af[jj][0] = *(const bf16x8*)((const char*)LDS + (buf)*32768 + R_*128 + ((kq)^sw_)); \
    af[jj][1] = *(const bf16x8*)((const char*)LDS + (buf)*32768 + R_*128 + ((64+kq)^sw_)); }}
// load all 4 B frags (n=0..3), both k-slices (once per K-tile, reused across 4 phases)
#define LDB(buf) { _Pragma("unroll") for (int nn=0;nn<4;++nn){ \
    const int R_ = wcol*64 + nn*16 + l15; const int sw_ = ((R_>>2)&1)<<5; \
    bfr[nn][0] = *(const bf16x8*)((const char*)LDS + 65536 + (buf)*32768 + R_*128 + ((kq)^sw_)); \
    bfr[nn][1] = *(const bf16x8*)((const char*)LDS + 65536 + (buf)*32768 + R_*128 + ((64+kq)^sw_)); }}
#define MMA(q) { __builtin_amdgcn_s_setprio(1); \
    _Pragma("unroll") for (int jj=0;jj<2;++jj) _Pragma("unroll") for (int nn=0;nn<4;++nn){ \
      acc[(q)*2+jj][nn] = __builtin_amdgcn_mfma_f32_16x16x32_bf16(af[jj][0], bfr[nn][0], acc[(q)*2+jj][nn],0,0,0); \
      acc[(q)*2+jj][nn] = __builtin_amdgcn_mfma_f32_16x16x32_bf16(af[jj][1], bfr[nn][1], acc[(q)*2+jj][nn],0,0,0); } \
    __builtin_amdgcn_s_setprio(0); }

template<int EPI>
__global__ __launch_bounds__(512, 2) void k_gemm8(
    const unsigned short* __restrict__ A, const unsigned short* __restrict__ Bt, int K,
    unsigned short* __restrict__ hb, unsigned short* __restrict__ htext,
    const int* __restrict__ sid, const int* __restrict__ eid,
    const float* __restrict__ spk, const float* __restrict__ emo)
{
  __shared__ unsigned short LDS[65536];   // 128 KiB
  const int t = threadIdx.x;
  const int lane = t & 63, w = t >> 6;
  const int wrow = w >> 2, wcol = w & 3;

  // bijective XCD-chunked swizzle (gridDim.x % 8 == 0), col-fastest (3 col panels)
  const int bid = blockIdx.x;
  const int cpx = gridDim.x >> 3;
  const int wg = (bid & 7) * cpx + (bid >> 3);
  const int by = wg / 3, bx = wg - by * 3;
  const int brow = by * 256, bcol = bx * 256;

  f32x4 acc[8][4];
  #pragma unroll
  for (int m = 0; m < 8; ++m)
    #pragma unroll
    for (int n = 0; n < 4; ++n) acc[m][n] = f32x4{0.f,0.f,0.f,0.f};

  // staging: thread t covers row (t>>3) of a 64-row issue, cols 8*(t&7)..+8,
  // with source column pre-swizzled so linear LDS ends up st_16x32-swizzled.
  const int srow = t >> 3;
  const int scol = ((t & 7) * 8) ^ (((t >> 5) & 1) << 4);
  const unsigned short* aS = A  + (size_t)(brow + srow) * K + scol;
  const unsigned short* bS = Bt + (size_t)(bcol + srow) * K + scol;
  unsigned short* dA = LDS + (size_t)w * 512;        // + buf*16384 + half*8192 (+4096 for 2nd issue)
  unsigned short* dB = dA + 32768;
  const int l15 = lane & 15, kq = (lane >> 4) * 16;  // kq in bytes
  const int nkt = K >> 6, niter = nkt >> 1;

  bf16x8 af[2][2], bfr[4][2];

  // prologue: B(0), A(0), B(1); A(1) is issued in-loop at ph1/2 (steady-state shape)
  STG_B(0,0,0); STG_B(0,1,0);
  STG_A(0,0,0); STG_A(0,1,0);
  STG_B(1,0,1); STG_B(1,1,1);
  WAITV4;                       // tile 0 fully landed; B(1) (4 loads) may fly
  BAR;

  for (int i = 0; i < niter; ++i){
    const int t1 = 2*i+1;
    const int t2 = (2*i+2 < nkt) ? 2*i+2 : nkt-1;   // tail: re-fetch valid tile, data unused
    const int t3 = (2*i+3 < nkt) ? 2*i+3 : nkt-1;
    // ---- tile 2i from buf0 ----
    LDA(0,0); LDB(0); STG_A(1,0,t1);                 // buf1.A freed at prev ph8
    BAR; WAITL; MMA(0); BAR;                         // ph1
    LDA(0,1);         STG_A(1,1,t1);
    BAR; WAITL; MMA(1); BAR;                         // ph2
    LDA(0,2);         STG_B(0,0,t2);                 // buf0.B freed at ph1
    BAR; WAITL; MMA(2); BAR;                         // ph3
    LDA(0,3);         STG_B(0,1,t2);
    BAR; WAITL; MMA(3);
    WAITV4; BAR;                                     // ph4: A(t1) landed (leaves B(t2) x4)
    // ---- tile 2i+1 from buf1 ----
    LDA(1,0); LDB(1); STG_A(0,0,t2);                 // buf0.A freed at ph4
    BAR; WAITL; MMA(0); BAR;                         // ph5
    LDA(1,1);         STG_A(0,1,t2);
    BAR; WAITL; MMA(1); BAR;                         // ph6
    LDA(1,2);         STG_B(1,0,t3);                 // buf1.B freed at ph5
    BAR; WAITL; MMA(2); BAR;                         // ph7
    LDA(1,3);         STG_B(1,1,t3);
    BAR; WAITL; MMA(3);
    WAITV4; BAR;                                     // ph8: A(t2)+B(t2) landed (leaves B(t3) x4)
  }
  WAITV0;  // drain tail prefetches before exit

  // epilogue: C/D layout col=lane&15, row=(lane>>4)*4+reg
  #pragma unroll
  for (int m = 0; m < 8; ++m){
    #pragma unroll
    for (int n = 0; n < 4; ++n){
      const int col = bcol + wcol*64 + n*16 + l15;
      #pragma unroll
      for (int j = 0; j < 4; ++j){
        const int row = brow + wrow*128 + m*16 + ((lane>>4)*4) + j;
        float v = acc[m][n][j];
        if (EPI == 0){
          float e = spk[sid[row] * 768 + col] + emo[eid[row] * 768 + col];
          v = fmaxf(v + e, 0.f);
          const unsigned short b = f2bf(v);
          hb[(size_t)row * 768 + col] = b;
          htext[(size_t)row * 768 + col] = b;
        } else {
          v = fmaxf(v, 0.f) + bf2f(hb[(size_t)row * 768 + col]);
          hb[(size_t)row * 768 + col] = f2bf(v);
        }
      }
    }
  }
}

// ================= 128x128 m97-style GEMM for the small (M=1024) shapes =================
// EPI 2: z = relu(acc + bias) -> obf at col base 3840, stride 4608 (edge_repr)
// EPI 3: hid = relu(acc + bias) -> of32 stride 768
template<int EPI>
__global__ __launch_bounds__(256) void k_gemm(
    const unsigned short* __restrict__ A, const unsigned short* __restrict__ Bt, int K,
    const float* __restrict__ bias,
    unsigned short* __restrict__ obf, float* __restrict__ of32)
{
  __shared__ unsigned short As[128*64];
  __shared__ unsigned short Bs[128*64];
  const int t = threadIdx.x;
  const int lane = t & 63, wave = t >> 6;

  const int bid = blockIdx.x;
  const int cpx = gridDim.x >> 3;
  const int wg = (bid & 7) * cpx + (bid >> 3);
  const int by = wg / 6;
  const int bx = wg - by * 6;
  const int brow = by * 128;
  const int bcol = bx * 128;

  const int wr = (wave >> 1) * 64, wc = (wave & 1) * 64;

  f32x4 acc[4][4];
  #pragma unroll
  for (int m = 0; m < 4; ++m)
    #pragma unroll
    for (int n = 0; n < 4; ++n)
      acc[m][n] = f32x4{0.f, 0.f, 0.f, 0.f};

  const int srow = wave * 8 + (lane >> 3);
  const int scol = (lane & 7) * 8;
  const int nkt = K >> 6;

  const unsigned short* a0 = A  + (size_t)(brow + srow) * K + scol;
  const unsigned short* b0 = Bt + (size_t)(bcol + srow) * K + scol;
  unsigned short* asdst = As + wave * 512;
  unsigned short* bsdst = Bs + wave * 512;

  for (int kt = 0; kt < nkt; ++kt){
    const unsigned short* ak = a0 + kt * 64;
    const unsigned short* bk = b0 + kt * 64;
    #pragma unroll
    for (int i = 0; i < 4; ++i)
      gld_lds16(ak + (size_t)i * 32 * K, asdst + i * 2048);
    #pragma unroll
    for (int i = 0; i < 4; ++i)
      gld_lds16(bk + (size_t)i * 32 * K, bsdst + i * 2048);
    __syncthreads();

    #pragma unroll
    for (int ks = 0; ks < 2; ++ks){
      bf16x8 af[4], bfr[4];
      const int kb = ks * 64 + ((lane >> 4) * 16);
      #pragma unroll
      for (int m = 0; m < 4; ++m)
        af[m] = *(const bf16x8*)((const char*)As + (wr + m * 16 + (lane & 15)) * 128 + kb);
      #pragma unroll
      for (int n = 0; n < 4; ++n)
        bfr[n] = *(const bf16x8*)((const char*)Bs + (wc + n * 16 + (lane & 15)) * 128 + kb);
      #pragma unroll
      for (int m = 0; m < 4; ++m)
        #pragma unroll
        for (int n = 0; n < 4; ++n)
          acc[m][n] = __builtin_amdgcn_mfma_f32_16x16x32_bf16(af[m], bfr[n], acc[m][n], 0, 0, 0);
    }
    __syncthreads();
  }

  #pragma unroll
  for (int m = 0; m < 4; ++m){
    #pragma unroll
    for (int n = 0; n < 4; ++n){
      int col = bcol + wc + n * 16 + (lane & 15);
      #pragma unroll
      for (int j = 0; j < 4; ++j){
        int row = brow + wr + m * 16 + ((lane >> 4) * 4) + j;
        float v = acc[m][n][j];
        if (EPI == 2){
          v = fmaxf(v + bias[col], 0.f);
          obf[(size_t)row * 4608 + 3840 + col] = f2bf(v);
        } else {
          v = fmaxf(v + bias[col], 0.f);
          of32[(size_t)row * 768 + col] = v;
        }
      }
    }
  }
}

// ---------------- per-graph segment sum + build bf16 [h | msg] A-buffer
// Source is now bf16 hb: stage 48KB via bf16x8 copies, sum from LDS.
__global__ __launch_bounds__(256) void k_scatter(const unsigned short* __restrict__ hb,
                                                 const int* __restrict__ esrc,
                                                 const int* __restrict__ etgt,
                                                 unsigned short* __restrict__ acat){
  __shared__ unsigned short hsm[32 * 768];   // 48KB
  __shared__ int cnt[32];
  __shared__ unsigned char lst[32][64];
  const int g = blockIdx.x, t = threadIdx.x;
  const unsigned short* src = hb + (size_t)g * 32 * 768;
  #pragma unroll
  for (int i = 0; i < 12; ++i){
    const int o = (i * 256 + t) * 8;
    *(bf16x8*)(hsm + o) = *(const bf16x8*)(src + o);
  }
  if (t < 32) cnt[t] = 0;
  __syncthreads();
  if (t < 64){
    const int e = g * 64 + t;
    const int s = esrc[e] & 31, tg = etgt[e] & 31;   // intra-graph local ids
    const int slot = atomicAdd(&cnt[tg], 1);
    lst[tg][slot] = (unsigned char)s;
  }
  __syncthreads();
  for (int n = 0; n < 32; ++n){
    float s0 = 0.f, s1 = 0.f, s2 = 0.f;
    const int c = cnt[n];
    for (int e = 0; e < c; ++e){
      const unsigned short* r = hsm + (int)lst[n][e] * 768;
      s0 += bf2f(r[t]); s1 += bf2f(r[t + 256]); s2 += bf2f(r[t + 512]);
    }
    unsigned short* oa = acat + (size_t)(g * 32 + n) * 1536;
    const unsigned short* hr = hsm + n * 768;
    oa[t]       = hr[t];
    oa[t + 256] = hr[t + 256];
    oa[t + 512] = hr[t + 512];
    oa[768 + t]       = f2bf(s0);
    oa[768 + t + 256] = f2bf(s1);
    oa[768 + t + 512] = f2bf(s2);
  }
}

// ---------------- per-graph: dist + gather h_c/h_t/h_dist into edge_repr
__global__ __launch_bounds__(256) void k_build(const unsigned short* __restrict__ hb,
                                               const unsigned short* __restrict__ htext,
                                               const int* __restrict__ tni,
                                               const int* __restrict__ esrc,
                                               const int* __restrict__ etgt,
                                               const float* __restrict__ dist_emb,
                                               unsigned short* __restrict__ er){
  int g = blockIdx.x;
  int t = threadIdx.x;
  __shared__ int s_dist;
  int c = tni[g * 2 + 0], tt = tni[g * 2 + 1];
  if (t == 0){
    // reference quirk: first_edge indexed with LOCAL node ids -> graph 0's edges only
    int cu = c, tu = tt;
    for (int e = 0; e < 64; ++e){ if (esrc[e] == c){ cu = etgt[e]; break; } }
    for (int e = 0; e < 64; ++e){ if (esrc[e] == tt){ tu = etgt[e]; break; } }
    int d = cu - tu; if (d < 0) d = -d; if (d > 31) d = 31;
    s_dist = d;
  }
  __syncthreads();
  size_t rc = (size_t)(g * 32 + c) * 768, rt = (size_t)(g * 32 + tt) * 768;
  unsigned short* o = er + (size_t)g * 4608;
  int d = s_dist;
  for (int i = t; i < 768; i += 256){
    o[i]        = hb[rc + i];
    o[768 + i]  = htext[rc + i];
    o[1536 + i] = hb[rt + i];
    o[2304 + i] = htext[rt + i];
    o[3072 + i] = f2bf(dist_emb[(size_t)d * 768 + i]);
  }
}

// ---------------- logits: out[i] = hid[i,:] . W_p2 + b_p2
__global__ __launch_bounds__(256) void k_logits(const float* __restrict__ hid,
                                                const float* __restrict__ wp2,
                                                const float* __restrict__ bp2,
                                                float* __restrict__ out){
  int row = blockIdx.x * 4 + (threadIdx.x >> 6);
  int lane = threadIdx.x & 63;
  const float* r = hid + (size_t)row * 768;
  float s = 0.f;
  for (int j = lane; j < 768; j += 64) s += r[j] * wp2[j];
  #pragma unroll
  for (int off = 32; off; off >>= 1) s += __shfl_down(s, off);
  if (lane == 0) out[row] = s + bp2[0];
}

extern "C" void kernel_launch(void* const* d_in, const int* in_sizes, int n_in,
                              void* d_out, int out_size, void* d_ws, size_t ws_size,
                              hipStream_t stream){
  const float* x        = (const float*)d_in[0];
  const int*   sid      = (const int*)d_in[1];
  const int*   eid      = (const int*)d_in[2];
  const int*   esrc     = (const int*)d_in[3];
  const int*   etgt     = esrc + EE;
  const int*   tni      = (const int*)d_in[4];
  const float* expl     = (const float*)d_in[5];
  const float* W_sem    = (const float*)d_in[6];
  const float* spk      = (const float*)d_in[7];
  const float* emo      = (const float*)d_in[8];
  const float* w_self   = (const float*)d_in[9];
  const float* w_nbr    = (const float*)d_in[10];
  const float* dist_emb = (const float*)d_in[11];
  const float* W_expl   = (const float*)d_in[12];
  const float* b_expl   = (const float*)d_in[13];
  const float* W_p1     = (const float*)d_in[14];
  const float* b_p1     = (const float*)d_in[15];
  const float* W_p2     = (const float*)d_in[16];
  const float* b_p2     = (const float*)d_in[17];

  char* ws = (char*)d_ws;
  size_t off = 0;
  auto alloc = [&](size_t bytes) -> void* {
    void* p = ws + off; off += (bytes + 255) & ~(size_t)255; return p;
  };
  unsigned short* hb    = (unsigned short*)alloc((size_t)NN * HH * 2);
  unsigned short* htext = (unsigned short*)alloc((size_t)NN * HH * 2);
  unsigned short* acat  = (unsigned short*)alloc((size_t)NN * KCAT * 2);
  unsigned short* WsemT = (unsigned short*)alloc((size_t)HH * KSEM * 2);
  unsigned short* WcatT = (unsigned short*)alloc((size_t)3 * HH * KCAT * 2);
  unsigned short* WexplT= (unsigned short*)alloc((size_t)HH * HH * 2);
  unsigned short* Wp1T  = (unsigned short*)alloc((size_t)HH * KP1 * 2);
  unsigned short* erepr = (unsigned short*)alloc((size_t)BB * KP1 * 2);
  float*          hid   = (float*)alloc((size_t)BB * HH * 4);
  unsigned short* explbf= (unsigned short*)alloc((size_t)BB * HH * 2);
  // xbf aliases acat: only live until sem GEMM completes; acat first written after.
  unsigned short* xbf   = acat;
  (void)ws_size; (void)in_sizes; (void)n_in; (void)out_size;

  // weight transposes (f32 -> bf16, [K][768] -> [768][K])
  k_transpose<<<dim3(KSEM/32, 24), 256, 0, stream>>>(W_sem, WsemT, KSEM, KSEM, 0);
  for (int l = 0; l < 3; ++l){
    k_transpose<<<dim3(24, 24), 256, 0, stream>>>(w_self + (size_t)l*HH*HH, WcatT + (size_t)l*HH*KCAT, HH, KCAT, 0);
    k_transpose<<<dim3(24, 24), 256, 0, stream>>>(w_nbr  + (size_t)l*HH*HH, WcatT + (size_t)l*HH*KCAT, HH, KCAT, HH);
  }
  k_transpose<<<dim3(24, 24), 256, 0, stream>>>(W_expl, WexplT, HH, HH, 0);
  k_transpose<<<dim3(KP1/32, 24), 256, 0, stream>>>(W_p1, Wp1T, KP1, KP1, 0);

  // activation casts f32 -> bf16
  k_cast<<<(NN*KSEM/8 + 255)/256, 256, 0, stream>>>(x, xbf, NN*KSEM/8);
  k_cast<<<(BB*HH/8 + 255)/256, 256, 0, stream>>>(expl, explbf, BB*HH/8);

  // h_text = relu(x @ W_sem + spk + emo)  [256^2 8-phase]
  k_gemm8<0><<<3*(NN/256), 512, 0, stream>>>(xbf, WsemT, KSEM,
      hb, htext, sid, eid, spk, emo);

  // 3 GNN layers  [256^2 8-phase]
  for (int l = 0; l < 3; ++l){
    k_scatter<<<BB, 256, 0, stream>>>(hb, esrc, etgt, acat);
    k_gemm8<1><<<3*(NN/256), 512, 0, stream>>>(acat, WcatT + (size_t)l*HH*KCAT, KCAT,
        hb, nullptr, nullptr, nullptr, nullptr, nullptr);
  }

  // z_teacher into edge_repr cols [3840,4608)  [128^2]
  k_gemm<2><<<6*(BB/128), 256, 0, stream>>>(explbf, WexplT, HH, b_expl, erepr, nullptr);

  // gather h_c/h_t/h_dist into edge_repr cols [0,3840)
  k_build<<<BB, 256, 0, stream>>>(hb, htext, tni, esrc, etgt, dist_emb, erepr);

  // hid = relu(edge_repr @ W_p1 + b_p1)  [128^2]
  k_gemm<3><<<6*(BB/128), 256, 0, stream>>>(erepr, Wp1T, KP1, b_p1, nullptr, hid);

  // logits
  k_logits<<<BB/4, 256, 0, stream>>>(hid, W_p2, b_p2, (float*)d_out);
}